// Round 4
// baseline (508.665 us; speedup 1.0000x reference)
//
#include <hip/hip_runtime.h>
#include <math.h>

typedef unsigned short ushort_t;
typedef __attribute__((ext_vector_type(4))) float f32x4;
typedef __attribute__((ext_vector_type(8))) short short8;

#define MFMA16(a, b, c) __builtin_amdgcn_mfma_f32_16x16x32_bf16((a), (b), (c), 0, 0, 0)

// Problem dims (fixed)
constexpr int kB = 8;
constexpr int kC = 256;
constexpr int kM = 128;
constexpr int kN = 16384;

// ws layout (bytes, 256-aligned). Total ~98.6 MB.
constexpr size_t kOffS    = 0;          // fp32 [8][128][256]
constexpr size_t kOffMatF = 1048576;    // fp32 [8][256][128]
constexpr size_t kOffKsum = 2097152;    // fp32 [8][128]
constexpr size_t kOffXsum = 2101248;    // fp32 [8][256]
constexpr size_t kOffVsum = 2109440;    // fp32 [8][256]
constexpr size_t kOffWkb  = 2117632;    // bf16 [128][256]
constexpr size_t kOffWqb  = 2183168;    // bf16 [128][256]
constexpr size_t kOffMatT = 2248704;    // bf16 [8][256][128]
constexpr size_t kOffKn   = 2772992;    // bf16 [8][128][16384]
constexpr size_t kOffXb16 = 36327424;   // bf16 [8][256][16384]

__device__ __forceinline__ ushort_t f2bf(float f) {
  union { float f; unsigned u; } v; v.f = f;
  unsigned r = v.u + 0x7fffu + ((v.u >> 16) & 1u);
  return (ushort_t)(r >> 16);
}
__device__ __forceinline__ float bf2f(ushort_t h) {
  union { float f; unsigned u; } v; v.u = ((unsigned)h) << 16;
  return v.f;
}

// Barrier that drains LDS only (lgkmcnt(0)); global stores/loads stay in flight.
__device__ __forceinline__ void sync_lds() {
  __atomic_signal_fence(__ATOMIC_SEQ_CST);
  __builtin_amdgcn_s_waitcnt(0xc07f);  // lgkmcnt(0), vmcnt/expcnt untouched
  __builtin_amdgcn_s_barrier();
  __atomic_signal_fence(__ATOMIC_SEQ_CST);
}

// ---------------- K0: zero accumulators + cast weights to bf16 ---------------
__global__ void k0_init(const float* __restrict__ Wq, const float* __restrict__ Wk,
                        float* __restrict__ ws_f, ushort_t* __restrict__ Wkb,
                        ushort_t* __restrict__ Wqb) {
  int i = blockIdx.x * 256 + threadIdx.x;  // 262144 threads
  // zero S (262144 f) + matF (262144 f) + Ksum/xsum (3072 f), all contiguous
  ws_f[i] = 0.0f;
  ws_f[i + 262144] = 0.0f;
  if (i < 3072) ws_f[524288 + i] = 0.0f;
  if (i < kM * kC) {
    Wkb[i] = f2bf(Wk[i]);
    Wqb[i] = f2bf(Wq[i]);
  }
}

// ---------------- K1a: K-proj (MFMA) -> L2-norm -> write Kn + xb16 -----------
// grid (64, 8), block 512 (8 waves; wave w owns K rows 16w..16w+15).
// No accumulator state -> low VGPR -> 3 blocks/CU (24 waves) for latency hiding.
__global__ __launch_bounds__(512, 6)
void k1a_proj(const float* __restrict__ x, const float* __restrict__ bk,
              const ushort_t* __restrict__ Wkb, ushort_t* __restrict__ KnG,
              ushort_t* __restrict__ xb16, float* __restrict__ Ksum,
              float* __restrict__ xsum) {
  __shared__ __align__(16) ushort_t xb_t[32][256];   // [px][ch ^ key<<3]
  __shared__ __align__(16) ushort_t knb[128][40];    // [Krow][px]
  __shared__ __align__(16) float red[32][12];        // [px][wave]

  const int t = threadIdx.x;
  const int b = blockIdx.y;
  const int lane = t & 63, w = t >> 6, quad = lane >> 4, l16 = lane & 15;
  const int r8 = t >> 3;        // channel row-in-64
  const int px0 = 4 * (t & 7);  // owned pixel group
  const int key01 = ((px0 >> 1) & 7) << 3;   // verified swizzle (r2/r3 passed)
  const int key23 = key01 ^ 8;
  const int rk = ((l16 >> 1) & 7) << 3;
  const int krow = 16 * w + (lane >> 2);     // Kn write-out: row
  const int kch = (lane & 3) * 8;            // Kn write-out: px chunk

  float bk_r[4];
#pragma unroll
  for (int r = 0; r < 4; ++r) bk_r[r] = bk[16 * w + 4 * quad + r];
  float ksump[4] = {0.f, 0.f, 0.f, 0.f};
  float xs_p[4] = {0.f, 0.f, 0.f, 0.f};

  const float* xg = x + ((size_t)(b * kC) + r8) * kN + blockIdx.x * 256 + px0;
  ushort_t* xw = xb16 + ((size_t)(b * kC) + r8) * kN + blockIdx.x * 256 + px0;

  for (int ti = 0; ti < 8; ++ti) {
    const int n0 = blockIdx.x * 256 + ti * 32;
    sync_lds();  // xb_t consumers of prev tile done
#pragma unroll
    for (int p = 0; p < 4; ++p) {
      float4 v = *(const float4*)(xg + (size_t)p * 64 * kN + ti * 32);
      const int rp = 64 * p + r8;
      xs_p[p] += v.x + v.y + v.z + v.w;
      ushort_t u0 = f2bf(v.x), u1 = f2bf(v.y), u2 = f2bf(v.z), u3 = f2bf(v.w);
      uint2 pk;
      pk.x = (unsigned)u0 | ((unsigned)u1 << 16);
      pk.y = (unsigned)u2 | ((unsigned)u3 << 16);
      *(uint2*)(xw + (size_t)p * 64 * kN + ti * 32) = pk;   // bf16 x for k1b/k3
      xb_t[px0 + 0][rp ^ key01] = u0;
      xb_t[px0 + 1][rp ^ key01] = u1;
      xb_t[px0 + 2][rp ^ key23] = u2;
      xb_t[px0 + 3][rp ^ key23] = u3;
    }
    sync_lds();  // stage done

    // GEMM1: K[128x32] = Wk * x
    f32x4 acc1[2] = {{0.f, 0.f, 0.f, 0.f}, {0.f, 0.f, 0.f, 0.f}};
    const ushort_t* wkbase = Wkb + (16 * w + l16) * 256 + quad * 8;
#pragma unroll
    for (int ks = 0; ks < 8; ++ks) {
      short8 a = *(const short8*)(wkbase + ks * 32);
      short8 b0 = *(const short8*)&xb_t[l16][(ks * 32 + quad * 8) ^ rk];
      short8 b1 = *(const short8*)&xb_t[16 + l16][(ks * 32 + quad * 8) ^ rk];
      acc1[0] = MFMA16(a, b0, acc1[0]);
      acc1[1] = MFMA16(a, b1, acc1[1]);
    }
    float k0v[4], k1v[4];
    float ssq0 = 0.f, ssq1 = 0.f;
#pragma unroll
    for (int r = 0; r < 4; ++r) {
      k0v[r] = acc1[0][r] + bk_r[r];
      k1v[r] = acc1[1][r] + bk_r[r];
      ssq0 += k0v[r] * k0v[r];
      ssq1 += k1v[r] * k1v[r];
    }
    ssq0 += __shfl_xor(ssq0, 16); ssq0 += __shfl_xor(ssq0, 32);
    ssq1 += __shfl_xor(ssq1, 16); ssq1 += __shfl_xor(ssq1, 32);
    if (quad == 0) { red[l16][w] = ssq0; red[16 + l16][w] = ssq1; }
    sync_lds();  // red ready

    f32x4 ra = *(const f32x4*)&red[l16][0];
    f32x4 rb = *(const f32x4*)&red[l16][4];
    f32x4 rc = *(const f32x4*)&red[16 + l16][0];
    f32x4 rd = *(const f32x4*)&red[16 + l16][4];
    const float iv0 = rsqrtf(ra[0] + ra[1] + ra[2] + ra[3] + rb[0] + rb[1] + rb[2] + rb[3]);
    const float iv1 = rsqrtf(rc[0] + rc[1] + rc[2] + rc[3] + rd[0] + rd[1] + rd[2] + rd[3]);
#pragma unroll
    for (int r = 0; r < 4; ++r) {
      float kn0 = k0v[r] * iv0, kn1 = k1v[r] * iv1;
      ksump[r] += kn0 + kn1;
      knb[16 * w + 4 * quad + r][l16] = f2bf(kn0);
      knb[16 * w + 4 * quad + r][16 + l16] = f2bf(kn1);
    }
    // knb rows 16w..16w+15 are wave-private; DS pipe is in-order per wave.
    __builtin_amdgcn_s_waitcnt(0xc07f);
    // write-out: 16B per lane, 64B segments per Kn row
    short8 kv8 = *(const short8*)&knb[krow][kch];
    *(short8*)(KnG + ((size_t)b * kM + krow) * kN + n0 + kch) = kv8;
  }

#pragma unroll
  for (int r = 0; r < 4; ++r) {
    float v = ksump[r];
    v += __shfl_xor(v, 1); v += __shfl_xor(v, 2);
    v += __shfl_xor(v, 4); v += __shfl_xor(v, 8);
    if (l16 == 0) atomicAdd(&Ksum[b * kM + 16 * w + 4 * quad + r], v);
  }
#pragma unroll
  for (int p = 0; p < 4; ++p) {
    float v = xs_p[p];
    v += __shfl_xor(v, 1); v += __shfl_xor(v, 2); v += __shfl_xor(v, 4);
    if ((t & 7) == 0) atomicAdd(&xsum[b * kC + 64 * p + r8], v);
  }
}

// ---------------- K1b: S[m][c] += sum_px Kn[m][px] * x[c][px] ----------------
// Both operands px-major = natural layout: NO LDS, NO barriers, pure streaming
// GEMM with 16 independent MFMA chains/wave. grid (64, 8), block 512:
// wave w owns m-rows 16w..16w+15 over all 256 c; block owns a 256-px slice.
__global__ __launch_bounds__(512, 4)
void k1b_S(const ushort_t* __restrict__ KnG, const ushort_t* __restrict__ xb16,
           float* __restrict__ S) {
  const int t = threadIdx.x;
  const int b = blockIdx.y;
  const int lane = t & 63, w = t >> 6, quad = lane >> 4, l16 = lane & 15;
  const int px0 = blockIdx.x * 256;

  f32x4 acc[16];
#pragma unroll
  for (int ct = 0; ct < 16; ++ct) acc[ct] = (f32x4){0.f, 0.f, 0.f, 0.f};

  const ushort_t* arow = KnG + ((size_t)b * kM + 16 * w + l16) * kN + px0 + quad * 8;
  const ushort_t* brow = xb16 + ((size_t)b * kC + l16) * kN + px0 + quad * 8;

#pragma unroll 2
  for (int kk = 0; kk < 8; ++kk) {
    short8 a2 = *(const short8*)(arow + kk * 32);
#pragma unroll
    for (int ct = 0; ct < 16; ++ct) {
      short8 b2 = *(const short8*)(brow + (size_t)ct * 16 * kN + kk * 32);
      acc[ct] = MFMA16(a2, b2, acc[ct]);
    }
  }

  float* Sb = S + (size_t)b * kM * kC;
#pragma unroll
  for (int ct = 0; ct < 16; ++ct)
#pragma unroll
    for (int r = 0; r < 4; ++r)
      atomicAdd(&Sb[(16 * w + 4 * quad + r) * 256 + ct * 16 + l16], acc[ct][r]);
}

// ---------------- K2: matF += partial(S*Wv^T) via hi/lo bf16 MFMA ------------
// c-contraction split x4 -> 1024 blocks (vs 256) for occupancy; fp32 atomics
// keep accuracy. Blocks 1024..1031 compute vsum = Wv*xsum + N*bv instead.
__global__ __launch_bounds__(256, 4)
void k2_matrix(const float* __restrict__ S, const float* __restrict__ Wv,
               const float* __restrict__ xsum, const float* __restrict__ bv,
               float* __restrict__ matF, float* __restrict__ vsum) {
  const int bx = blockIdx.x;
  const int t = threadIdx.x;
  if (bx >= 1024) {  // vsum blocks (one per batch)
    const int b = bx - 1024;
    const float4* wr = (const float4*)(Wv + (size_t)t * 256);
    const float4* xs = (const float4*)(xsum + b * 256);
    float v = 0.f;
#pragma unroll 8
    for (int i = 0; i < 64; ++i) {
      float4 a = wr[i], xx = xs[i];
      v += a.x * xx.x + a.y * xx.y + a.z * xx.z + a.w * xx.w;
    }
    vsum[b * 256 + t] = v + 16384.f * bv[t];
    return;
  }
  const int lane = t & 63, w = t >> 6, quad = lane >> 4, l16 = lane & 15;
  const int b = bx >> 7, rr_ = bx & 127;
  const int ct = rr_ >> 3, mt = (rr_ >> 2) & 1, kq = rr_ & 3;
  const int c0 = ct * 16;
  const int m0 = mt * 64 + w * 16;

  const float* arow = Wv + (size_t)(c0 + l16) * 256 + kq * 64 + quad * 8;
  const float* brow = S + ((size_t)b * kM + m0 + l16) * 256 + kq * 64 + quad * 8;

  f32x4 acc = (f32x4){0.f, 0.f, 0.f, 0.f};
#pragma unroll
  for (int ks = 0; ks < 2; ++ks) {
    float4 a0 = *(const float4*)(arow + ks * 32);
    float4 a1 = *(const float4*)(arow + ks * 32 + 4);
    float4 b0 = *(const float4*)(brow + ks * 32);
    float4 b1 = *(const float4*)(brow + ks * 32 + 4);
    float av[8] = {a0.x, a0.y, a0.z, a0.w, a1.x, a1.y, a1.z, a1.w};
    float bw[8] = {b0.x, b0.y, b0.z, b0.w, b1.x, b1.y, b1.z, b1.w};
    short8 ah, al, bh, bl;
#pragma unroll
    for (int i = 0; i < 8; ++i) {
      ushort_t h = f2bf(av[i]);
      ah[i] = (short)h;
      al[i] = (short)f2bf(av[i] - bf2f(h));
      ushort_t g = f2bf(bw[i]);
      bh[i] = (short)g;
      bl[i] = (short)f2bf(bw[i] - bf2f(g));
    }
    acc = MFMA16(ah, bh, acc);
    acc = MFMA16(ah, bl, acc);
    acc = MFMA16(al, bh, acc);
  }
#pragma unroll
  for (int r = 0; r < 4; ++r)
    atomicAdd(&matF[((size_t)b * kC + c0 + 4 * quad + r) * kM + m0 + l16], acc[r]);
}

// ---------------- K2b: matT = bf16(matF + Ksum*bv^T) -------------------------
__global__ __launch_bounds__(256)
void k2b_cast(const float* __restrict__ matF, const float* __restrict__ Ksum,
              const float* __restrict__ bv, ushort_t* __restrict__ matT) {
  const int idx = blockIdx.x * 256 + threadIdx.x;  // 262144 = 8*256*128
  const int m = idx & 127, c = (idx >> 7) & 255, b = idx >> 15;
  matT[idx] = f2bf(matF[idx] + Ksum[b * 128 + m] * bv[c]);
}

// ---------------- K3: Q-proj -> norm/tailor -> out = g*t*(vsum + matT*qn) ----
// grid (64, 8), block 512. Reads pre-converted bf16 x (half the bytes, no f2bf).
__global__ __launch_bounds__(512, 2)
void k3_out(const ushort_t* __restrict__ xb16, const float* __restrict__ bq,
            const ushort_t* __restrict__ Wqb, const ushort_t* __restrict__ matT,
            const float* __restrict__ Ksum, const float* __restrict__ vsum,
            const float* __restrict__ gamma, float* __restrict__ out) {
  __shared__ __align__(16) ushort_t xb_t[32][256];   // [px][ch ^ key<<3]
  __shared__ __align__(16) ushort_t qnb[32][136];    // [px][m]
  __shared__ __align__(16) float red[32][12];
  __shared__ __align__(16) float red2[32][12];

  const int t = threadIdx.x;
  const int b = blockIdx.y;
  const int lane = t & 63, w = t >> 6, quad = lane >> 4, l16 = lane & 15;
  const int r8 = t >> 3;
  const int px0 = 4 * (t & 7);
  const int key01 = ((px0 >> 1) & 7) << 3;
  const int key23 = key01 ^ 8;
  const int rk = ((l16 >> 1) & 7) << 3;
  const float gm = gamma[0];

  float bq_r[4], ks_r[4], vs_r[2][4];
#pragma unroll
  for (int r = 0; r < 4; ++r) {
    bq_r[r] = bq[16 * w + 4 * quad + r];
    ks_r[r] = Ksum[b * kM + 16 * w + 4 * quad + r] + 1e-6f;
  }
#pragma unroll
  for (int mi = 0; mi < 2; ++mi)
#pragma unroll
    for (int r = 0; r < 4; ++r)
      vs_r[mi][r] = vsum[b * kC + (2 * w + mi) * 16 + 4 * quad + r];

  const ushort_t* xg = xb16 + ((size_t)(b * kC) + r8) * kN + blockIdx.x * 256 + px0;

  uint2 bufA[4], bufB[4];
#pragma unroll
  for (int p = 0; p < 4; ++p)
    bufA[p] = *(const uint2*)(xg + (size_t)p * 64 * kN);

  auto step = [&](int ti, uint2 (&cur)[4], uint2 (&nxt)[4]) {
    const int n0 = blockIdx.x * 256 + ti * 32;
    sync_lds();
    if (ti < 7) {
#pragma unroll
      for (int p = 0; p < 4; ++p)
        nxt[p] = *(const uint2*)(xg + (size_t)p * 64 * kN + (ti + 1) * 32);
    }
#pragma unroll
    for (int p = 0; p < 4; ++p) {
      uint2 v = cur[p];
      const int rp = 64 * p + r8;
      xb_t[px0 + 0][rp ^ key01] = (ushort_t)(v.x & 0xffffu);
      xb_t[px0 + 1][rp ^ key01] = (ushort_t)(v.x >> 16);
      xb_t[px0 + 2][rp ^ key23] = (ushort_t)(v.y & 0xffffu);
      xb_t[px0 + 3][rp ^ key23] = (ushort_t)(v.y >> 16);
    }
    sync_lds();

    // Q projection
    f32x4 acc1[2] = {{0.f, 0.f, 0.f, 0.f}, {0.f, 0.f, 0.f, 0.f}};
    const ushort_t* wqbase = Wqb + (16 * w + l16) * 256 + quad * 8;
#pragma unroll
    for (int ks = 0; ks < 8; ++ks) {
      short8 a = *(const short8*)(wqbase + ks * 32);
      short8 b0 = *(const short8*)&xb_t[l16][(ks * 32 + quad * 8) ^ rk];
      short8 b1 = *(const short8*)&xb_t[16 + l16][(ks * 32 + quad * 8) ^ rk];
      acc1[0] = MFMA16(a, b0, acc1[0]);
      acc1[1] = MFMA16(a, b1, acc1[1]);
    }
    float q0v[4], q1v[4];
    float ssq0 = 0.f, ssq1 = 0.f, dot0 = 0.f, dot1 = 0.f;
#pragma unroll
    for (int r = 0; r < 4; ++r) {
      q0v[r] = acc1[0][r] + bq_r[r];
      q1v[r] = acc1[1][r] + bq_r[r];
      ssq0 += q0v[r] * q0v[r]; ssq1 += q1v[r] * q1v[r];
      dot0 += q0v[r] * ks_r[r]; dot1 += q1v[r] * ks_r[r];
    }
    ssq0 += __shfl_xor(ssq0, 16); ssq0 += __shfl_xor(ssq0, 32);
    ssq1 += __shfl_xor(ssq1, 16); ssq1 += __shfl_xor(ssq1, 32);
    dot0 += __shfl_xor(dot0, 16); dot0 += __shfl_xor(dot0, 32);
    dot1 += __shfl_xor(dot1, 16); dot1 += __shfl_xor(dot1, 32);
    if (quad == 0) {
      red[l16][w] = ssq0;  red[16 + l16][w] = ssq1;
      red2[l16][w] = dot0; red2[16 + l16][w] = dot1;
    }
    sync_lds();
    f32x4 ra = *(const f32x4*)&red[l16][0];
    f32x4 rb = *(const f32x4*)&red[l16][4];
    f32x4 rc = *(const f32x4*)&red[16 + l16][0];
    f32x4 rd = *(const f32x4*)&red[16 + l16][4];
    f32x4 da = *(const f32x4*)&red2[l16][0];
    f32x4 db = *(const f32x4*)&red2[l16][4];
    f32x4 dc = *(const f32x4*)&red2[16 + l16][0];
    f32x4 dd = *(const f32x4*)&red2[16 + l16][4];
    const float iv0 = rsqrtf(ra[0] + ra[1] + ra[2] + ra[3] + rb[0] + rb[1] + rb[2] + rb[3]);
    const float iv1 = rsqrtf(rc[0] + rc[1] + rc[2] + rc[3] + rd[0] + rd[1] + rd[2] + rd[3]);
    const float d0 = da[0] + da[1] + da[2] + da[3] + db[0] + db[1] + db[2] + db[3];
    const float d1 = dc[0] + dc[1] + dc[2] + dc[3] + dd[0] + dd[1] + dd[2] + dd[3];
    const float tl0 = 1.f / (16384.f + d0 * iv0);
    const float tl1 = 1.f / (16384.f + d1 * iv1);
    {
      ushort_t q0b[4], q1b[4];
#pragma unroll
      for (int r = 0; r < 4; ++r) {
        q0b[r] = f2bf(q0v[r] * iv0);
        q1b[r] = f2bf(q1v[r] * iv1);
      }
      uint2 p0, p1;
      p0.x = (unsigned)q0b[0] | ((unsigned)q0b[1] << 16);
      p0.y = (unsigned)q0b[2] | ((unsigned)q0b[3] << 16);
      p1.x = (unsigned)q1b[0] | ((unsigned)q1b[1] << 16);
      p1.y = (unsigned)q1b[2] | ((unsigned)q1b[3] << 16);
      *(uint2*)&qnb[l16][16 * w + 4 * quad] = p0;
      *(uint2*)&qnb[16 + l16][16 * w + 4 * quad] = p1;
    }
    sync_lds();  // qnb is read cross-wave

    // out-GEMM: O[256 x 32] = matT * qn
    f32x4 accO[2][2];
#pragma unroll
    for (int mi = 0; mi < 2; ++mi)
#pragma unroll
      for (int nt = 0; nt < 2; ++nt) accO[mi][nt] = (f32x4){0.f, 0.f, 0.f, 0.f};
    const ushort_t* mrow0 = matT + ((size_t)b * kC + (2 * w) * 16 + l16) * kM + quad * 8;
    const ushort_t* mrow1 = mrow0 + 16 * kM;
#pragma unroll
    for (int ks = 0; ks < 4; ++ks) {
      short8 b0 = *(const short8*)&qnb[l16][ks * 32 + quad * 8];
      short8 b1 = *(const short8*)&qnb[16 + l16][ks * 32 + quad * 8];
      short8 a0 = *(const short8*)(mrow0 + ks * 32);
      short8 a1 = *(const short8*)(mrow1 + ks * 32);
      accO[0][0] = MFMA16(a0, b0, accO[0][0]);
      accO[0][1] = MFMA16(a0, b1, accO[0][1]);
      accO[1][0] = MFMA16(a1, b0, accO[1][0]);
      accO[1][1] = MFMA16(a1, b1, accO[1][1]);
    }
#pragma unroll
    for (int mi = 0; mi < 2; ++mi) {
#pragma unroll
      for (int r = 0; r < 4; ++r) {
        const int c = (2 * w + mi) * 16 + 4 * quad + r;
        size_t base = ((size_t)(b * kC + c)) * kN + n0;
        out[base + l16] = gm * tl0 * (vs_r[mi][r] + accO[mi][0][r]);
        out[base + 16 + l16] = gm * tl1 * (vs_r[mi][r] + accO[mi][1][r]);
      }
    }
  };

  for (int ti = 0; ti < 8; ti += 2) {
    step(ti, bufA, bufB);
    step(ti + 1, bufB, bufA);
  }
}

extern "C" void kernel_launch(void* const* d_in, const int* in_sizes, int n_in,
                              void* d_out, int out_size, void* d_ws, size_t ws_size,
                              hipStream_t stream) {
  (void)in_sizes; (void)n_in; (void)out_size; (void)ws_size;
  const float* x     = (const float*)d_in[0];
  const float* Wq    = (const float*)d_in[1];
  const float* bq    = (const float*)d_in[2];
  const float* Wk    = (const float*)d_in[3];
  const float* bk    = (const float*)d_in[4];
  const float* Wv    = (const float*)d_in[5];
  const float* bv    = (const float*)d_in[6];
  const float* gamma = (const float*)d_in[7];
  float* out = (float*)d_out;

  char* wsb = (char*)d_ws;
  float*    S    = (float*)(wsb + kOffS);
  float*    matF = (float*)(wsb + kOffMatF);
  float*    Ksum = (float*)(wsb + kOffKsum);
  float*    xsum = (float*)(wsb + kOffXsum);
  float*    vsum = (float*)(wsb + kOffVsum);
  ushort_t* Wkb  = (ushort_t*)(wsb + kOffWkb);
  ushort_t* Wqb  = (ushort_t*)(wsb + kOffWqb);
  ushort_t* matT = (ushort_t*)(wsb + kOffMatT);
  ushort_t* KnG  = (ushort_t*)(wsb + kOffKn);
  ushort_t* xb16 = (ushort_t*)(wsb + kOffXb16);

  k0_init<<<1024, 256, 0, stream>>>(Wq, Wk, (float*)wsb, Wkb, Wqb);
  k1a_proj<<<dim3(64, 8), 512, 0, stream>>>(x, bk, Wkb, KnG, xb16, Ksum, xsum);
  k1b_S<<<dim3(64, 8), 512, 0, stream>>>(KnG, xb16, S);
  k2_matrix<<<1032, 256, 0, stream>>>(S, Wv, xsum, bv, matF, vsum);
  k2b_cast<<<1024, 256, 0, stream>>>(matF, Ksum, bv, matT);
  k3_out<<<dim3(64, 8), 512, 0, stream>>>(xb16, bq, Wqb, matT, Ksum, vsum, gamma, out);
}

// Round 5
// 458.831 us; speedup vs baseline: 1.1086x; 1.1086x over previous
//
#include <hip/hip_runtime.h>
#include <math.h>

typedef unsigned short ushort_t;
typedef __attribute__((ext_vector_type(4))) float f32x4;
typedef __attribute__((ext_vector_type(8))) short short8;

#define MFMA16(a, b, c) __builtin_amdgcn_mfma_f32_16x16x32_bf16((a), (b), (c), 0, 0, 0)

// Problem dims (fixed)
constexpr int kB = 8;
constexpr int kC = 256;
constexpr int kM = 128;
constexpr int kN = 16384;

// ws layout (bytes, 256-aligned). Total ~2.8 MB.
constexpr size_t kOffS    = 0;          // fp32 [8][128][256]
constexpr size_t kOffMatF = 1048576;    // fp32 [8][256][128]
constexpr size_t kOffKsum = 2097152;    // fp32 [8][128]
constexpr size_t kOffXsum = 2101248;    // fp32 [8][256]
constexpr size_t kOffVsum = 2109440;    // fp32 [8][256]
constexpr size_t kOffWkb  = 2117632;    // bf16 [128][256]
constexpr size_t kOffWqb  = 2183168;    // bf16 [128][256]
constexpr size_t kOffMatT = 2248704;    // bf16 [8][256][128]

__device__ __forceinline__ ushort_t f2bf(float f) {
  union { float f; unsigned u; } v; v.f = f;
  unsigned r = v.u + 0x7fffu + ((v.u >> 16) & 1u);
  return (ushort_t)(r >> 16);
}
__device__ __forceinline__ float bf2f(ushort_t h) {
  union { float f; unsigned u; } v; v.u = ((unsigned)h) << 16;
  return v.f;
}

// Barrier that drains LDS only (lgkmcnt(0)); global loads stay in flight.
__device__ __forceinline__ void sync_lds() {
  __atomic_signal_fence(__ATOMIC_SEQ_CST);
  __builtin_amdgcn_s_waitcnt(0xc07f);  // lgkmcnt(0), vmcnt/expcnt untouched
  __builtin_amdgcn_s_barrier();
  __atomic_signal_fence(__ATOMIC_SEQ_CST);
}

// ---------------- K0: zero accumulators + cast weights to bf16 ---------------
__global__ void k0_init(const float* __restrict__ Wq, const float* __restrict__ Wk,
                        float* __restrict__ ws_f, ushort_t* __restrict__ Wkb,
                        ushort_t* __restrict__ Wqb) {
  int i = blockIdx.x * 256 + threadIdx.x;  // 262144 threads
  // zero S (262144 f) + matF (262144 f) + Ksum/xsum (3072 f)
  ws_f[i] = 0.0f;
  ws_f[i + 262144] = 0.0f;
  if (i < 3072) ws_f[524288 + i] = 0.0f;
  if (i < kM * kC) {
    Wkb[i] = f2bf(Wk[i]);
    Wqb[i] = f2bf(Wq[i]);
  }
}

// ---------------- K1: K-proj (MFMA) -> L2-norm -> S += Kn * x^T (MFMA) -------
// grid (128, 8), block 512. Block pair (2s, 2s+1) shares px-slice s; each
// block accumulates S for HALF the c-columns -> accS[8] = 32 AGPRs (was 64).
// Total regs ~96 VGPR + 32 AGPR = 128 -> 4 waves/SIMD -> 2 blocks/CU (was 1:
// r0-r3's 112 VGPR + 64 AGPR = 176 capped residency at 1 block, which is why
// MfmaUtil/VALU/HBM all sat <20% regardless of conflicts/atomics/barriers).
// GEMM1+staging run redundantly in both pair-members (both pipes ~idle: free).
__global__ __launch_bounds__(512, 4)
void k1_acc(const float* __restrict__ x, const float* __restrict__ bk,
            const ushort_t* __restrict__ Wkb, float* __restrict__ S,
            float* __restrict__ Ksum, float* __restrict__ xsum) {
  // Bank layouts all verified r0-r3: xb_n pitch 40 (reads 8/bank uniform,
  // writes 4/bank min); xb_t pitch 256 + XOR key ((row>>1)&7)<<3 (reads
  // 8/bank uniform, writes 2/bank free); knb pitch 40.
  __shared__ __align__(16) ushort_t xb_n[256][40];   // [ch][px]  (px-fastest)
  __shared__ __align__(16) ushort_t xb_t[32][256];   // [px][ch ^ key<<3]
  __shared__ __align__(16) ushort_t knb[128][40];    // [Krow][px]
  __shared__ __align__(16) float red[32][12];        // [px][wave]

  const int t = threadIdx.x;
  const int b = blockIdx.y;
  const int slice = blockIdx.x >> 1;   // px-slice 0..63
  const int chalf = blockIdx.x & 1;    // c-half 0/1
  const int lane = t & 63, w = t >> 6, quad = lane >> 4, l16 = lane & 15;
  const int r8 = t >> 3;        // channel row-in-64 (0..63)
  const int px0 = 4 * (t & 7);  // owned pixel group
  const int key01 = ((px0 >> 1) & 7) << 3;
  const int key23 = key01 ^ 8;
  const int rk = ((l16 >> 1) & 7) << 3;

  float bk_r[4];
#pragma unroll
  for (int r = 0; r < 4; ++r) bk_r[r] = bk[16 * w + 4 * quad + r];

  f32x4 accS[8];
#pragma unroll
  for (int ct = 0; ct < 8; ++ct) accS[ct] = (f32x4){0.f, 0.f, 0.f, 0.f};
  float ksump[4] = {0.f, 0.f, 0.f, 0.f};
  float xs_p[4] = {0.f, 0.f, 0.f, 0.f};

  const float* xg = x + ((size_t)(b * kC) + r8) * kN + slice * 256 + px0;

  // single prefetch buffer (saves 16 VGPR vs double); refilled right after
  // stage consumes it, lands during GEMM1+norm+GEMM2 (ample slack).
  float4 buf[4];
#pragma unroll
  for (int p = 0; p < 4; ++p)
    buf[p] = *(const float4*)(xg + (size_t)p * 64 * kN);

  for (int ti = 0; ti < 8; ++ti) {
    sync_lds();  // previous tile's LDS consumers done
#pragma unroll
    for (int p = 0; p < 4; ++p) {
      float4 v = buf[p];
      const int rp = 64 * p + r8;
      xs_p[p] += v.x + v.y + v.z + v.w;
      ushort_t u0 = f2bf(v.x), u1 = f2bf(v.y), u2 = f2bf(v.z), u3 = f2bf(v.w);
      uint2 pk;
      pk.x = (unsigned)u0 | ((unsigned)u1 << 16);
      pk.y = (unsigned)u2 | ((unsigned)u3 << 16);
      *(uint2*)&xb_n[rp][px0] = pk;
      xb_t[px0 + 0][rp ^ key01] = u0;
      xb_t[px0 + 1][rp ^ key01] = u1;
      xb_t[px0 + 2][rp ^ key23] = u2;
      xb_t[px0 + 3][rp ^ key23] = u3;
    }
    if (ti < 7) {
#pragma unroll
      for (int p = 0; p < 4; ++p)
        buf[p] = *(const float4*)(xg + (size_t)p * 64 * kN + (ti + 1) * 32);
    }
    sync_lds();  // stage done

    // ---- GEMM1: K[128x32] = Wk * x (wave w owns K rows 16w..16w+15) ----
    f32x4 acc1[2] = {{0.f, 0.f, 0.f, 0.f}, {0.f, 0.f, 0.f, 0.f}};
    const ushort_t* wkbase = Wkb + (16 * w + l16) * 256 + quad * 8;
#pragma unroll
    for (int ks = 0; ks < 8; ++ks) {
      short8 a = *(const short8*)(wkbase + ks * 32);
      short8 b0 = *(const short8*)&xb_t[l16][(ks * 32 + quad * 8) ^ rk];
      short8 b1 = *(const short8*)&xb_t[16 + l16][(ks * 32 + quad * 8) ^ rk];
      acc1[0] = MFMA16(a, b0, acc1[0]);
      acc1[1] = MFMA16(a, b1, acc1[1]);
    }
    float k0v[4], k1v[4];
    float ssq0 = 0.f, ssq1 = 0.f;
#pragma unroll
    for (int r = 0; r < 4; ++r) {
      k0v[r] = acc1[0][r] + bk_r[r];
      k1v[r] = acc1[1][r] + bk_r[r];
      ssq0 += k0v[r] * k0v[r];
      ssq1 += k1v[r] * k1v[r];
    }
    ssq0 += __shfl_xor(ssq0, 16); ssq0 += __shfl_xor(ssq0, 32);
    ssq1 += __shfl_xor(ssq1, 16); ssq1 += __shfl_xor(ssq1, 32);
    if (quad == 0) { red[l16][w] = ssq0; red[16 + l16][w] = ssq1; }
    sync_lds();  // red ready

    f32x4 ra = *(const f32x4*)&red[l16][0];
    f32x4 rb = *(const f32x4*)&red[l16][4];
    f32x4 rc = *(const f32x4*)&red[16 + l16][0];
    f32x4 rd = *(const f32x4*)&red[16 + l16][4];
    const float iv0 = rsqrtf(ra[0] + ra[1] + ra[2] + ra[3] + rb[0] + rb[1] + rb[2] + rb[3]);
    const float iv1 = rsqrtf(rc[0] + rc[1] + rc[2] + rc[3] + rd[0] + rd[1] + rd[2] + rd[3]);
#pragma unroll
    for (int r = 0; r < 4; ++r) {
      float kn0 = k0v[r] * iv0, kn1 = k1v[r] * iv1;
      ksump[r] += kn0 + kn1;
      knb[16 * w + 4 * quad + r][l16] = f2bf(kn0);
      knb[16 * w + 4 * quad + r][16 + l16] = f2bf(kn1);
    }
    // knb rows 16w..16w+15 are wave-private: DS pipe is in-order per wave.
    __builtin_amdgcn_s_waitcnt(0xc07f);

    // ---- GEMM2: S[16 x 128] += Kn * x^T for this block's c-half ----
    short8 a2 = *(const short8*)&knb[16 * w + l16][quad * 8];
#pragma unroll
    for (int ct = 0; ct < 8; ++ct) {
      short8 b2 = *(const short8*)&xb_n[chalf * 128 + ct * 16 + l16][quad * 8];
      accS[ct] = MFMA16(a2, b2, accS[ct]);
    }
  }

  // ---- flush ----
  float* Sb = S + (size_t)b * kM * kC;
#pragma unroll
  for (int ct = 0; ct < 8; ++ct)
#pragma unroll
    for (int r = 0; r < 4; ++r)
      atomicAdd(&Sb[(16 * w + 4 * quad + r) * 256 + (chalf * 8 + ct) * 16 + l16],
                accS[ct][r]);
  if (chalf == 0) {  // pair-member 1 computed identical ksump/xs_p; flush once
#pragma unroll
    for (int r = 0; r < 4; ++r) {
      float v = ksump[r];
      v += __shfl_xor(v, 1); v += __shfl_xor(v, 2);
      v += __shfl_xor(v, 4); v += __shfl_xor(v, 8);
      if (l16 == 0) atomicAdd(&Ksum[b * kM + 16 * w + 4 * quad + r], v);
    }
#pragma unroll
    for (int p = 0; p < 4; ++p) {
      float v = xs_p[p];
      v += __shfl_xor(v, 1); v += __shfl_xor(v, 2); v += __shfl_xor(v, 4);
      if ((t & 7) == 0) atomicAdd(&xsum[b * kC + 64 * p + r8], v);
    }
  }
}

// ---------------- K2: matF += partial(S*Wv^T) via hi/lo bf16 MFMA ------------
// c-contraction split x4 -> 1024 blocks for occupancy (was 256 = 1 wave/SIMD,
// fully latency-exposed); fp32 atomics keep accuracy. Blocks 1024..1031
// compute vsum = Wv*xsum + N*bv. (Verified correct in r4 run.)
__global__ __launch_bounds__(256, 4)
void k2_matrix(const float* __restrict__ S, const float* __restrict__ Wv,
               const float* __restrict__ xsum, const float* __restrict__ bv,
               float* __restrict__ matF, float* __restrict__ vsum) {
  const int bx = blockIdx.x;
  const int t = threadIdx.x;
  if (bx >= 1024) {  // vsum blocks (one per batch)
    const int b = bx - 1024;
    const float4* wr = (const float4*)(Wv + (size_t)t * 256);
    const float4* xs = (const float4*)(xsum + b * 256);
    float v = 0.f;
#pragma unroll 8
    for (int i = 0; i < 64; ++i) {
      float4 a = wr[i], xx = xs[i];
      v += a.x * xx.x + a.y * xx.y + a.z * xx.z + a.w * xx.w;
    }
    vsum[b * 256 + t] = v + 16384.f * bv[t];
    return;
  }
  const int lane = t & 63, w = t >> 6, quad = lane >> 4, l16 = lane & 15;
  const int b = bx >> 7, rr_ = bx & 127;
  const int ct = rr_ >> 3, mt = (rr_ >> 2) & 1, kq = rr_ & 3;
  const int c0 = ct * 16;
  const int m0 = mt * 64 + w * 16;

  const float* arow = Wv + (size_t)(c0 + l16) * 256 + kq * 64 + quad * 8;
  const float* brow = S + ((size_t)b * kM + m0 + l16) * 256 + kq * 64 + quad * 8;

  f32x4 acc = (f32x4){0.f, 0.f, 0.f, 0.f};
#pragma unroll
  for (int ks = 0; ks < 2; ++ks) {
    float4 a0 = *(const float4*)(arow + ks * 32);
    float4 a1 = *(const float4*)(arow + ks * 32 + 4);
    float4 b0 = *(const float4*)(brow + ks * 32);
    float4 b1 = *(const float4*)(brow + ks * 32 + 4);
    float av[8] = {a0.x, a0.y, a0.z, a0.w, a1.x, a1.y, a1.z, a1.w};
    float bw[8] = {b0.x, b0.y, b0.z, b0.w, b1.x, b1.y, b1.z, b1.w};
    short8 ah, al, bh, bl;
#pragma unroll
    for (int i = 0; i < 8; ++i) {
      ushort_t h = f2bf(av[i]);
      ah[i] = (short)h;
      al[i] = (short)f2bf(av[i] - bf2f(h));
      ushort_t g = f2bf(bw[i]);
      bh[i] = (short)g;
      bl[i] = (short)f2bf(bw[i] - bf2f(g));
    }
    acc = MFMA16(ah, bh, acc);
    acc = MFMA16(ah, bl, acc);
    acc = MFMA16(al, bh, acc);
  }
#pragma unroll
  for (int r = 0; r < 4; ++r)
    atomicAdd(&matF[((size_t)b * kC + c0 + 4 * quad + r) * kM + m0 + l16], acc[r]);
}

// ---------------- K2b: matT = bf16(matF + Ksum*bv^T) -------------------------
__global__ __launch_bounds__(256)
void k2b_cast(const float* __restrict__ matF, const float* __restrict__ Ksum,
              const float* __restrict__ bv, ushort_t* __restrict__ matT) {
  const int idx = blockIdx.x * 256 + threadIdx.x;  // 262144 = 8*256*128
  const int m = idx & 127, c = (idx >> 7) & 255, b = idx >> 15;
  matT[idx] = f2bf(matF[idx] + Ksum[b * 128 + m] * bv[c]);
}

// ---------------- K3: Q-proj -> norm/tailor -> out = g*t*(vsum + matT*qn) ----
// grid (64, 8), block 512. Unchanged from r3 (proven 343-us config).
__global__ __launch_bounds__(512, 2)
void k3_out(const float* __restrict__ x, const float* __restrict__ bq,
            const ushort_t* __restrict__ Wqb, const ushort_t* __restrict__ matT,
            const float* __restrict__ Ksum, const float* __restrict__ vsum,
            const float* __restrict__ gamma, float* __restrict__ out) {
  __shared__ __align__(16) ushort_t xb_t[32][256];   // [px][ch ^ key<<3]
  __shared__ __align__(16) ushort_t qnb[32][136];    // [px][m]
  __shared__ __align__(16) float red[32][12];
  __shared__ __align__(16) float red2[32][12];

  const int t = threadIdx.x;
  const int b = blockIdx.y;
  const int lane = t & 63, w = t >> 6, quad = lane >> 4, l16 = lane & 15;
  const int r8 = t >> 3;
  const int px0 = 4 * (t & 7);
  const int key01 = ((px0 >> 1) & 7) << 3;
  const int key23 = key01 ^ 8;
  const int rk = ((l16 >> 1) & 7) << 3;
  const float gm = gamma[0];

  float bq_r[4], ks_r[4], vs_r[2][4];
#pragma unroll
  for (int r = 0; r < 4; ++r) {
    bq_r[r] = bq[16 * w + 4 * quad + r];
    ks_r[r] = Ksum[b * kM + 16 * w + 4 * quad + r] + 1e-6f;
  }
#pragma unroll
  for (int mi = 0; mi < 2; ++mi)
#pragma unroll
    for (int r = 0; r < 4; ++r)
      vs_r[mi][r] = vsum[b * kC + (2 * w + mi) * 16 + 4 * quad + r];

  const float* xg = x + ((size_t)(b * kC) + r8) * kN + blockIdx.x * 256 + px0;

  float4 bufA[4], bufB[4];
#pragma unroll
  for (int p = 0; p < 4; ++p)
    bufA[p] = *(const float4*)(xg + (size_t)p * 64 * kN);

  auto step = [&](int ti, float4 (&cur)[4], float4 (&nxt)[4]) {
    const int n0 = blockIdx.x * 256 + ti * 32;
    sync_lds();
    if (ti < 7) {
#pragma unroll
      for (int p = 0; p < 4; ++p)
        nxt[p] = *(const float4*)(xg + (size_t)p * 64 * kN + (ti + 1) * 32);
    }
#pragma unroll
    for (int p = 0; p < 4; ++p) {
      float4 v = cur[p];
      const int rp = 64 * p + r8;
      xb_t[px0 + 0][rp ^ key01] = f2bf(v.x);
      xb_t[px0 + 1][rp ^ key01] = f2bf(v.y);
      xb_t[px0 + 2][rp ^ key23] = f2bf(v.z);
      xb_t[px0 + 3][rp ^ key23] = f2bf(v.w);
    }
    sync_lds();

    // Q projection
    f32x4 acc1[2] = {{0.f, 0.f, 0.f, 0.f}, {0.f, 0.f, 0.f, 0.f}};
    const ushort_t* wqbase = Wqb + (16 * w + l16) * 256 + quad * 8;
#pragma unroll
    for (int ks = 0; ks < 8; ++ks) {
      short8 a = *(const short8*)(wqbase + ks * 32);
      short8 b0 = *(const short8*)&xb_t[l16][(ks * 32 + quad * 8) ^ rk];
      short8 b1 = *(const short8*)&xb_t[16 + l16][(ks * 32 + quad * 8) ^ rk];
      acc1[0] = MFMA16(a, b0, acc1[0]);
      acc1[1] = MFMA16(a, b1, acc1[1]);
    }
    float q0v[4], q1v[4];
    float ssq0 = 0.f, ssq1 = 0.f, dot0 = 0.f, dot1 = 0.f;
#pragma unroll
    for (int r = 0; r < 4; ++r) {
      q0v[r] = acc1[0][r] + bq_r[r];
      q1v[r] = acc1[1][r] + bq_r[r];
      ssq0 += q0v[r] * q0v[r]; ssq1 += q1v[r] * q1v[r];
      dot0 += q0v[r] * ks_r[r]; dot1 += q1v[r] * ks_r[r];
    }
    ssq0 += __shfl_xor(ssq0, 16); ssq0 += __shfl_xor(ssq0, 32);
    ssq1 += __shfl_xor(ssq1, 16); ssq1 += __shfl_xor(ssq1, 32);
    dot0 += __shfl_xor(dot0, 16); dot0 += __shfl_xor(dot0, 32);
    dot1 += __shfl_xor(dot1, 16); dot1 += __shfl_xor(dot1, 32);
    if (quad == 0) {
      red[l16][w] = ssq0;  red[16 + l16][w] = ssq1;
      red2[l16][w] = dot0; red2[16 + l16][w] = dot1;
    }
    sync_lds();
    f32x4 ra = *(const f32x4*)&red[l16][0];
    f32x4 rb = *(const f32x4*)&red[l16][4];
    f32x4 rc = *(const f32x4*)&red[16 + l16][0];
    f32x4 rd = *(const f32x4*)&red[16 + l16][4];
    f32x4 da = *(const f32x4*)&red2[l16][0];
    f32x4 db = *(const f32x4*)&red2[l16][4];
    f32x4 dc = *(const f32x4*)&red2[16 + l16][0];
    f32x4 dd = *(const f32x4*)&red2[16 + l16][4];
    const float iv0 = rsqrtf(ra[0] + ra[1] + ra[2] + ra[3] + rb[0] + rb[1] + rb[2] + rb[3]);
    const float iv1 = rsqrtf(rc[0] + rc[1] + rc[2] + rc[3] + rd[0] + rd[1] + rd[2] + rd[3]);
    const float d0 = da[0] + da[1] + da[2] + da[3] + db[0] + db[1] + db[2] + db[3];
    const float d1 = dc[0] + dc[1] + dc[2] + dc[3] + dd[0] + dd[1] + dd[2] + dd[3];
    const float tl0 = 1.f / (16384.f + d0 * iv0);
    const float tl1 = 1.f / (16384.f + d1 * iv1);
    {
      ushort_t q0b[4], q1b[4];
#pragma unroll
      for (int r = 0; r < 4; ++r) {
        q0b[r] = f2bf(q0v[r] * iv0);
        q1b[r] = f2bf(q1v[r] * iv1);
      }
      uint2 p0, p1;
      p0.x = (unsigned)q0b[0] | ((unsigned)q0b[1] << 16);
      p0.y = (unsigned)q0b[2] | ((unsigned)q0b[3] << 16);
      p1.x = (unsigned)q1b[0] | ((unsigned)q1b[1] << 16);
      p1.y = (unsigned)q1b[2] | ((unsigned)q1b[3] << 16);
      *(uint2*)&qnb[l16][16 * w + 4 * quad] = p0;
      *(uint2*)&qnb[16 + l16][16 * w + 4 * quad] = p1;
    }
    sync_lds();  // qnb is read cross-wave

    // out-GEMM: O[256 x 32] = matT * qn  (wave w owns c-tiles 2w, 2w+1)
    f32x4 accO[2][2];
#pragma unroll
    for (int mi = 0; mi < 2; ++mi)
#pragma unroll
      for (int nt = 0; nt < 2; ++nt) accO[mi][nt] = (f32x4){0.f, 0.f, 0.f, 0.f};
    const ushort_t* mrow0 = matT + ((size_t)b * kC + (2 * w) * 16 + l16) * kM + quad * 8;
    const ushort_t* mrow1 = mrow0 + 16 * kM;
#pragma unroll
    for (int ks = 0; ks < 4; ++ks) {
      short8 b0 = *(const short8*)&qnb[l16][ks * 32 + quad * 8];
      short8 b1 = *(const short8*)&qnb[16 + l16][ks * 32 + quad * 8];
      short8 a0 = *(const short8*)(mrow0 + ks * 32);
      short8 a1 = *(const short8*)(mrow1 + ks * 32);
      accO[0][0] = MFMA16(a0, b0, accO[0][0]);
      accO[0][1] = MFMA16(a0, b1, accO[0][1]);
      accO[1][0] = MFMA16(a1, b0, accO[1][0]);
      accO[1][1] = MFMA16(a1, b1, accO[1][1]);
    }
#pragma unroll
    for (int mi = 0; mi < 2; ++mi) {
#pragma unroll
      for (int r = 0; r < 4; ++r) {
        const int c = (2 * w + mi) * 16 + 4 * quad + r;
        size_t base = ((size_t)(b * kC + c)) * kN + n0;
        out[base + l16] = gm * tl0 * (vs_r[mi][r] + accO[mi][0][r]);
        out[base + 16 + l16] = gm * tl1 * (vs_r[mi][r] + accO[mi][1][r]);
      }
    }
  };

  for (int ti = 0; ti < 8; ti += 2) {
    step(ti, bufA, bufB);
    step(ti + 1, bufB, bufA);
  }
}

extern "C" void kernel_launch(void* const* d_in, const int* in_sizes, int n_in,
                              void* d_out, int out_size, void* d_ws, size_t ws_size,
                              hipStream_t stream) {
  (void)in_sizes; (void)n_in; (void)out_size; (void)ws_size;
  const float* x     = (const float*)d_in[0];
  const float* Wq    = (const float*)d_in[1];
  const float* bq    = (const float*)d_in[2];
  const float* Wk    = (const float*)d_in[3];
  const float* bk    = (const float*)d_in[4];
  const float* Wv    = (const float*)d_in[5];
  const float* bv    = (const float*)d_in[6];
  const float* gamma = (const float*)d_in[7];
  float* out = (float*)d_out;

  char* wsb = (char*)d_ws;
  float*    S    = (float*)(wsb + kOffS);
  float*    matF = (float*)(wsb + kOffMatF);
  float*    Ksum = (float*)(wsb + kOffKsum);
  float*    xsum = (float*)(wsb + kOffXsum);
  float*    vsum = (float*)(wsb + kOffVsum);
  ushort_t* Wkb  = (ushort_t*)(wsb + kOffWkb);
  ushort_t* Wqb  = (ushort_t*)(wsb + kOffWqb);
  ushort_t* matT = (ushort_t*)(wsb + kOffMatT);

  k0_init<<<1024, 256, 0, stream>>>(Wq, Wk, (float*)wsb, Wkb, Wqb);
  k1_acc<<<dim3(128, 8), 512, 0, stream>>>(x, bk, Wkb, S, Ksum, xsum);
  k2_matrix<<<1032, 256, 0, stream>>>(S, Wv, xsum, bv, matF, vsum);
  k2b_cast<<<1024, 256, 0, stream>>>(matF, Ksum, bv, matT);
  k3_out<<<dim3(64, 8), 512, 0, stream>>>(x, bq, Wqb, matT, Ksum, vsum, gamma, out);
}

// Round 6
// 451.469 us; speedup vs baseline: 1.1267x; 1.0163x over previous
//
#include <hip/hip_runtime.h>
#include <math.h>

typedef unsigned short ushort_t;
typedef __attribute__((ext_vector_type(4))) float f32x4;
typedef __attribute__((ext_vector_type(8))) short short8;

#define MFMA16(a, b, c) __builtin_amdgcn_mfma_f32_16x16x32_bf16((a), (b), (c), 0, 0, 0)

// Problem dims (fixed)
constexpr int kB = 8;
constexpr int kC = 256;
constexpr int kM = 128;
constexpr int kN = 16384;

// ws layout (bytes, 256-aligned). Total ~98.6 MB.
constexpr size_t kOffS    = 0;          // fp32 [8][128][256]
constexpr size_t kOffMatF = 1048576;    // fp32 [8][256][128]
constexpr size_t kOffKsum = 2097152;    // fp32 [8][128]
constexpr size_t kOffXsum = 2101248;    // fp32 [8][256]
constexpr size_t kOffVsum = 2109440;    // fp32 [8][256]
constexpr size_t kOffWkb  = 2117632;    // bf16 [128][256]
constexpr size_t kOffWqb  = 2183168;    // bf16 [128][256]
constexpr size_t kOffMatT = 2248704;    // bf16 [8][256][128]
constexpr size_t kOffKn   = 2772992;    // bf16 [8][128][16384]
constexpr size_t kOffXb16 = 36327424;   // bf16 [8][256][16384]

__device__ __forceinline__ ushort_t f2bf(float f) {
  union { float f; unsigned u; } v; v.f = f;
  unsigned r = v.u + 0x7fffu + ((v.u >> 16) & 1u);
  return (ushort_t)(r >> 16);
}
__device__ __forceinline__ float bf2f(ushort_t h) {
  union { float f; unsigned u; } v; v.u = ((unsigned)h) << 16;
  return v.f;
}

// Barrier that drains LDS only (lgkmcnt(0)); global stores/loads stay in flight.
__device__ __forceinline__ void sync_lds() {
  __atomic_signal_fence(__ATOMIC_SEQ_CST);
  __builtin_amdgcn_s_waitcnt(0xc07f);  // lgkmcnt(0), vmcnt/expcnt untouched
  __builtin_amdgcn_s_barrier();
  __atomic_signal_fence(__ATOMIC_SEQ_CST);
}

// ---------------- K0: zero accumulators + cast weights to bf16 ---------------
__global__ void k0_init(const float* __restrict__ Wq, const float* __restrict__ Wk,
                        float* __restrict__ ws_f, ushort_t* __restrict__ Wkb,
                        ushort_t* __restrict__ Wqb) {
  int i = blockIdx.x * 256 + threadIdx.x;  // 262144 threads
  // zero S (262144 f) + matF (262144 f) + Ksum/xsum (3072 f), all contiguous
  ws_f[i] = 0.0f;
  ws_f[i + 262144] = 0.0f;
  if (i < 3072) ws_f[524288 + i] = 0.0f;
  if (i < kM * kC) {
    Wkb[i] = f2bf(Wk[i]);
    Wqb[i] = f2bf(Wq[i]);
  }
}

// ---------------- K1a: K-proj (MFMA) -> L2-norm -> write Kn + xb16 -----------
// grid (64, 8), block 512 (8 waves; wave w owns K rows 16w..16w+15).
// NO min-waves launch bound: r4's (512,6) forced VGPR=40 -> total spill ->
// 347 MB traffic @ 166 us. Natural demand (~70 VGPR, no accumulator) gives
// high occupancy without any cap. (Kernel body identical to r4 = passed.)
__global__ __launch_bounds__(512)
void k1a_proj(const float* __restrict__ x, const float* __restrict__ bk,
              const ushort_t* __restrict__ Wkb, ushort_t* __restrict__ KnG,
              ushort_t* __restrict__ xb16, float* __restrict__ Ksum,
              float* __restrict__ xsum) {
  __shared__ __align__(16) ushort_t xb_t[32][256];   // [px][ch ^ key<<3]
  __shared__ __align__(16) ushort_t knb[128][40];    // [Krow][px]
  __shared__ __align__(16) float red[32][12];        // [px][wave]

  const int t = threadIdx.x;
  const int b = blockIdx.y;
  const int lane = t & 63, w = t >> 6, quad = lane >> 4, l16 = lane & 15;
  const int r8 = t >> 3;        // channel row-in-64
  const int px0 = 4 * (t & 7);  // owned pixel group
  const int key01 = ((px0 >> 1) & 7) << 3;   // verified swizzle (r2-r5 passed)
  const int key23 = key01 ^ 8;
  const int rk = ((l16 >> 1) & 7) << 3;
  const int krow = 16 * w + (lane >> 2);     // Kn write-out: row
  const int kch = (lane & 3) * 8;            // Kn write-out: px chunk

  float bk_r[4];
#pragma unroll
  for (int r = 0; r < 4; ++r) bk_r[r] = bk[16 * w + 4 * quad + r];
  float ksump[4] = {0.f, 0.f, 0.f, 0.f};
  float xs_p[4] = {0.f, 0.f, 0.f, 0.f};

  const float* xg = x + ((size_t)(b * kC) + r8) * kN + blockIdx.x * 256 + px0;
  ushort_t* xw = xb16 + ((size_t)(b * kC) + r8) * kN + blockIdx.x * 256 + px0;

  for (int ti = 0; ti < 8; ++ti) {
    const int n0 = blockIdx.x * 256 + ti * 32;
    sync_lds();  // xb_t consumers of prev tile done
#pragma unroll
    for (int p = 0; p < 4; ++p) {
      float4 v = *(const float4*)(xg + (size_t)p * 64 * kN + ti * 32);
      const int rp = 64 * p + r8;
      xs_p[p] += v.x + v.y + v.z + v.w;
      ushort_t u0 = f2bf(v.x), u1 = f2bf(v.y), u2 = f2bf(v.z), u3 = f2bf(v.w);
      uint2 pk;
      pk.x = (unsigned)u0 | ((unsigned)u1 << 16);
      pk.y = (unsigned)u2 | ((unsigned)u3 << 16);
      *(uint2*)(xw + (size_t)p * 64 * kN + ti * 32) = pk;   // bf16 x for k1b/k3
      xb_t[px0 + 0][rp ^ key01] = u0;
      xb_t[px0 + 1][rp ^ key01] = u1;
      xb_t[px0 + 2][rp ^ key23] = u2;
      xb_t[px0 + 3][rp ^ key23] = u3;
    }
    sync_lds();  // stage done

    // GEMM1: K[128x32] = Wk * x
    f32x4 acc1[2] = {{0.f, 0.f, 0.f, 0.f}, {0.f, 0.f, 0.f, 0.f}};
    const ushort_t* wkbase = Wkb + (16 * w + l16) * 256 + quad * 8;
#pragma unroll
    for (int ks = 0; ks < 8; ++ks) {
      short8 a = *(const short8*)(wkbase + ks * 32);
      short8 b0 = *(const short8*)&xb_t[l16][(ks * 32 + quad * 8) ^ rk];
      short8 b1 = *(const short8*)&xb_t[16 + l16][(ks * 32 + quad * 8) ^ rk];
      acc1[0] = MFMA16(a, b0, acc1[0]);
      acc1[1] = MFMA16(a, b1, acc1[1]);
    }
    float k0v[4], k1v[4];
    float ssq0 = 0.f, ssq1 = 0.f;
#pragma unroll
    for (int r = 0; r < 4; ++r) {
      k0v[r] = acc1[0][r] + bk_r[r];
      k1v[r] = acc1[1][r] + bk_r[r];
      ssq0 += k0v[r] * k0v[r];
      ssq1 += k1v[r] * k1v[r];
    }
    ssq0 += __shfl_xor(ssq0, 16); ssq0 += __shfl_xor(ssq0, 32);
    ssq1 += __shfl_xor(ssq1, 16); ssq1 += __shfl_xor(ssq1, 32);
    if (quad == 0) { red[l16][w] = ssq0; red[16 + l16][w] = ssq1; }
    sync_lds();  // red ready

    f32x4 ra = *(const f32x4*)&red[l16][0];
    f32x4 rb = *(const f32x4*)&red[l16][4];
    f32x4 rc = *(const f32x4*)&red[16 + l16][0];
    f32x4 rd = *(const f32x4*)&red[16 + l16][4];
    const float iv0 = rsqrtf(ra[0] + ra[1] + ra[2] + ra[3] + rb[0] + rb[1] + rb[2] + rb[3]);
    const float iv1 = rsqrtf(rc[0] + rc[1] + rc[2] + rc[3] + rd[0] + rd[1] + rd[2] + rd[3]);
#pragma unroll
    for (int r = 0; r < 4; ++r) {
      float kn0 = k0v[r] * iv0, kn1 = k1v[r] * iv1;
      ksump[r] += kn0 + kn1;
      knb[16 * w + 4 * quad + r][l16] = f2bf(kn0);
      knb[16 * w + 4 * quad + r][16 + l16] = f2bf(kn1);
    }
    // knb rows 16w..16w+15 are wave-private; DS pipe is in-order per wave.
    __builtin_amdgcn_s_waitcnt(0xc07f);
    // write-out: 16B per lane, 64B segments per Kn row
    short8 kv8 = *(const short8*)&knb[krow][kch];
    *(short8*)(KnG + ((size_t)b * kM + krow) * kN + n0 + kch) = kv8;
  }

#pragma unroll
  for (int r = 0; r < 4; ++r) {
    float v = ksump[r];
    v += __shfl_xor(v, 1); v += __shfl_xor(v, 2);
    v += __shfl_xor(v, 4); v += __shfl_xor(v, 8);
    if (l16 == 0) atomicAdd(&Ksum[b * kM + 16 * w + 4 * quad + r], v);
  }
#pragma unroll
  for (int p = 0; p < 4; ++p) {
    float v = xs_p[p];
    v += __shfl_xor(v, 1); v += __shfl_xor(v, 2); v += __shfl_xor(v, 4);
    if ((t & 7) == 0) atomicAdd(&xsum[b * kC + 64 * p + r8], v);
  }
}

// ---------------- K1b: S[m][c] += sum_px Kn[m][px] * x[c][px] ----------------
// Both operands px-major = natural layout: NO LDS, NO barriers, pure streaming
// GEMM with 16 independent MFMA chains/wave. ~30 arch VGPR + 64 AGPR < cap,
// fits 4 waves/SIMD naturally. grid (64, 8), block 512. (r4-verified.)
__global__ __launch_bounds__(512, 4)
void k1b_S(const ushort_t* __restrict__ KnG, const ushort_t* __restrict__ xb16,
           float* __restrict__ S) {
  const int t = threadIdx.x;
  const int b = blockIdx.y;
  const int lane = t & 63, w = t >> 6, quad = lane >> 4, l16 = lane & 15;
  const int px0 = blockIdx.x * 256;

  f32x4 acc[16];
#pragma unroll
  for (int ct = 0; ct < 16; ++ct) acc[ct] = (f32x4){0.f, 0.f, 0.f, 0.f};

  const ushort_t* arow = KnG + ((size_t)b * kM + 16 * w + l16) * kN + px0 + quad * 8;
  const ushort_t* brow = xb16 + ((size_t)b * kC + l16) * kN + px0 + quad * 8;

#pragma unroll 2
  for (int kk = 0; kk < 8; ++kk) {
    short8 a2 = *(const short8*)(arow + kk * 32);
#pragma unroll
    for (int ct = 0; ct < 16; ++ct) {
      short8 b2 = *(const short8*)(brow + (size_t)ct * 16 * kN + kk * 32);
      acc[ct] = MFMA16(a2, b2, acc[ct]);
    }
  }

  float* Sb = S + (size_t)b * kM * kC;
#pragma unroll
  for (int ct = 0; ct < 16; ++ct)
#pragma unroll
    for (int r = 0; r < 4; ++r)
      atomicAdd(&Sb[(16 * w + 4 * quad + r) * 256 + ct * 16 + l16], acc[ct][r]);
}

// ---------------- K2: matF += partial(S*Wv^T) via hi/lo bf16 MFMA ------------
// c-contraction split x4 -> 1024 blocks for occupancy; fp32 atomics keep
// accuracy. Blocks 1024..1031 compute vsum = Wv*xsum + N*bv. (r4/r5-verified.)
__global__ __launch_bounds__(256, 4)
void k2_matrix(const float* __restrict__ S, const float* __restrict__ Wv,
               const float* __restrict__ xsum, const float* __restrict__ bv,
               float* __restrict__ matF, float* __restrict__ vsum) {
  const int bx = blockIdx.x;
  const int t = threadIdx.x;
  if (bx >= 1024) {  // vsum blocks (one per batch)
    const int b = bx - 1024;
    const float4* wr = (const float4*)(Wv + (size_t)t * 256);
    const float4* xs = (const float4*)(xsum + b * 256);
    float v = 0.f;
#pragma unroll 8
    for (int i = 0; i < 64; ++i) {
      float4 a = wr[i], xx = xs[i];
      v += a.x * xx.x + a.y * xx.y + a.z * xx.z + a.w * xx.w;
    }
    vsum[b * 256 + t] = v + 16384.f * bv[t];
    return;
  }
  const int lane = t & 63, w = t >> 6, quad = lane >> 4, l16 = lane & 15;
  const int b = bx >> 7, rr_ = bx & 127;
  const int ct = rr_ >> 3, mt = (rr_ >> 2) & 1, kq = rr_ & 3;
  const int c0 = ct * 16;
  const int m0 = mt * 64 + w * 16;

  const float* arow = Wv + (size_t)(c0 + l16) * 256 + kq * 64 + quad * 8;
  const float* brow = S + ((size_t)b * kM + m0 + l16) * 256 + kq * 64 + quad * 8;

  f32x4 acc = (f32x4){0.f, 0.f, 0.f, 0.f};
#pragma unroll
  for (int ks = 0; ks < 2; ++ks) {
    float4 a0 = *(const float4*)(arow + ks * 32);
    float4 a1 = *(const float4*)(arow + ks * 32 + 4);
    float4 b0 = *(const float4*)(brow + ks * 32);
    float4 b1 = *(const float4*)(brow + ks * 32 + 4);
    float av[8] = {a0.x, a0.y, a0.z, a0.w, a1.x, a1.y, a1.z, a1.w};
    float bw[8] = {b0.x, b0.y, b0.z, b0.w, b1.x, b1.y, b1.z, b1.w};
    short8 ah, al, bh, bl;
#pragma unroll
    for (int i = 0; i < 8; ++i) {
      ushort_t h = f2bf(av[i]);
      ah[i] = (short)h;
      al[i] = (short)f2bf(av[i] - bf2f(h));
      ushort_t g = f2bf(bw[i]);
      bh[i] = (short)g;
      bl[i] = (short)f2bf(bw[i] - bf2f(g));
    }
    acc = MFMA16(ah, bh, acc);
    acc = MFMA16(ah, bl, acc);
    acc = MFMA16(al, bh, acc);
  }
#pragma unroll
  for (int r = 0; r < 4; ++r)
    atomicAdd(&matF[((size_t)b * kC + c0 + 4 * quad + r) * kM + m0 + l16], acc[r]);
}

// ---------------- K2b: matT = bf16(matF + Ksum*bv^T) -------------------------
__global__ __launch_bounds__(256)
void k2b_cast(const float* __restrict__ matF, const float* __restrict__ Ksum,
              const float* __restrict__ bv, ushort_t* __restrict__ matT) {
  const int idx = blockIdx.x * 256 + threadIdx.x;  // 262144 = 8*256*128
  const int m = idx & 127, c = (idx >> 7) & 255, b = idx >> 15;
  matT[idx] = f2bf(matF[idx] + Ksum[b * 128 + m] * bv[c]);
}

// ---------------- K3: Q-proj -> norm/tailor -> out = g*t*(vsum + matT*qn) ----
// grid (64, 8), block 512. Reads pre-converted bf16 x (half the bytes, no
// f2bf on the staging path). (r4-verified body.)
__global__ __launch_bounds__(512, 2)
void k3_out(const ushort_t* __restrict__ xb16, const float* __restrict__ bq,
            const ushort_t* __restrict__ Wqb, const ushort_t* __restrict__ matT,
            const float* __restrict__ Ksum, const float* __restrict__ vsum,
            const float* __restrict__ gamma, float* __restrict__ out) {
  __shared__ __align__(16) ushort_t xb_t[32][256];   // [px][ch ^ key<<3]
  __shared__ __align__(16) ushort_t qnb[32][136];    // [px][m]
  __shared__ __align__(16) float red[32][12];
  __shared__ __align__(16) float red2[32][12];

  const int t = threadIdx.x;
  const int b = blockIdx.y;
  const int lane = t & 63, w = t >> 6, quad = lane >> 4, l16 = lane & 15;
  const int r8 = t >> 3;
  const int px0 = 4 * (t & 7);
  const int key01 = ((px0 >> 1) & 7) << 3;
  const int key23 = key01 ^ 8;
  const int rk = ((l16 >> 1) & 7) << 3;
  const float gm = gamma[0];

  float bq_r[4], ks_r[4], vs_r[2][4];
#pragma unroll
  for (int r = 0; r < 4; ++r) {
    bq_r[r] = bq[16 * w + 4 * quad + r];
    ks_r[r] = Ksum[b * kM + 16 * w + 4 * quad + r] + 1e-6f;
  }
#pragma unroll
  for (int mi = 0; mi < 2; ++mi)
#pragma unroll
    for (int r = 0; r < 4; ++r)
      vs_r[mi][r] = vsum[b * kC + (2 * w + mi) * 16 + 4 * quad + r];

  const ushort_t* xg = xb16 + ((size_t)(b * kC) + r8) * kN + blockIdx.x * 256 + px0;

  uint2 bufA[4], bufB[4];
#pragma unroll
  for (int p = 0; p < 4; ++p)
    bufA[p] = *(const uint2*)(xg + (size_t)p * 64 * kN);

  auto step = [&](int ti, uint2 (&cur)[4], uint2 (&nxt)[4]) {
    const int n0 = blockIdx.x * 256 + ti * 32;
    sync_lds();
    if (ti < 7) {
#pragma unroll
      for (int p = 0; p < 4; ++p)
        nxt[p] = *(const uint2*)(xg + (size_t)p * 64 * kN + (ti + 1) * 32);
    }
#pragma unroll
    for (int p = 0; p < 4; ++p) {
      uint2 v = cur[p];
      const int rp = 64 * p + r8;
      xb_t[px0 + 0][rp ^ key01] = (ushort_t)(v.x & 0xffffu);
      xb_t[px0 + 1][rp ^ key01] = (ushort_t)(v.x >> 16);
      xb_t[px0 + 2][rp ^ key23] = (ushort_t)(v.y & 0xffffu);
      xb_t[px0 + 3][rp ^ key23] = (ushort_t)(v.y >> 16);
    }
    sync_lds();

    // Q projection
    f32x4 acc1[2] = {{0.f, 0.f, 0.f, 0.f}, {0.f, 0.f, 0.f, 0.f}};
    const ushort_t* wqbase = Wqb + (16 * w + l16) * 256 + quad * 8;
#pragma unroll
    for (int ks = 0; ks < 8; ++ks) {
      short8 a = *(const short8*)(wqbase + ks * 32);
      short8 b0 = *(const short8*)&xb_t[l16][(ks * 32 + quad * 8) ^ rk];
      short8 b1 = *(const short8*)&xb_t[16 + l16][(ks * 32 + quad * 8) ^ rk];
      acc1[0] = MFMA16(a, b0, acc1[0]);
      acc1[1] = MFMA16(a, b1, acc1[1]);
    }
    float q0v[4], q1v[4];
    float ssq0 = 0.f, ssq1 = 0.f, dot0 = 0.f, dot1 = 0.f;
#pragma unroll
    for (int r = 0; r < 4; ++r) {
      q0v[r] = acc1[0][r] + bq_r[r];
      q1v[r] = acc1[1][r] + bq_r[r];
      ssq0 += q0v[r] * q0v[r]; ssq1 += q1v[r] * q1v[r];
      dot0 += q0v[r] * ks_r[r]; dot1 += q1v[r] * ks_r[r];
    }
    ssq0 += __shfl_xor(ssq0, 16); ssq0 += __shfl_xor(ssq0, 32);
    ssq1 += __shfl_xor(ssq1, 16); ssq1 += __shfl_xor(ssq1, 32);
    dot0 += __shfl_xor(dot0, 16); dot0 += __shfl_xor(dot0, 32);
    dot1 += __shfl_xor(dot1, 16); dot1 += __shfl_xor(dot1, 32);
    if (quad == 0) {
      red[l16][w] = ssq0;  red[16 + l16][w] = ssq1;
      red2[l16][w] = dot0; red2[16 + l16][w] = dot1;
    }
    sync_lds();
    f32x4 ra = *(const f32x4*)&red[l16][0];
    f32x4 rb = *(const f32x4*)&red[l16][4];
    f32x4 rc = *(const f32x4*)&red[16 + l16][0];
    f32x4 rd = *(const f32x4*)&red[16 + l16][4];
    f32x4 da = *(const f32x4*)&red2[l16][0];
    f32x4 db = *(const f32x4*)&red2[l16][4];
    f32x4 dc = *(const f32x4*)&red2[16 + l16][0];
    f32x4 dd = *(const f32x4*)&red2[16 + l16][4];
    const float iv0 = rsqrtf(ra[0] + ra[1] + ra[2] + ra[3] + rb[0] + rb[1] + rb[2] + rb[3]);
    const float iv1 = rsqrtf(rc[0] + rc[1] + rc[2] + rc[3] + rd[0] + rd[1] + rd[2] + rd[3]);
    const float d0 = da[0] + da[1] + da[2] + da[3] + db[0] + db[1] + db[2] + db[3];
    const float d1 = dc[0] + dc[1] + dc[2] + dc[3] + dd[0] + dd[1] + dd[2] + dd[3];
    const float tl0 = 1.f / (16384.f + d0 * iv0);
    const float tl1 = 1.f / (16384.f + d1 * iv1);
    {
      ushort_t q0b[4], q1b[4];
#pragma unroll
      for (int r = 0; r < 4; ++r) {
        q0b[r] = f2bf(q0v[r] * iv0);
        q1b[r] = f2bf(q1v[r] * iv1);
      }
      uint2 p0, p1;
      p0.x = (unsigned)q0b[0] | ((unsigned)q0b[1] << 16);
      p0.y = (unsigned)q0b[2] | ((unsigned)q0b[3] << 16);
      p1.x = (unsigned)q1b[0] | ((unsigned)q1b[1] << 16);
      p1.y = (unsigned)q1b[2] | ((unsigned)q1b[3] << 16);
      *(uint2*)&qnb[l16][16 * w + 4 * quad] = p0;
      *(uint2*)&qnb[16 + l16][16 * w + 4 * quad] = p1;
    }
    sync_lds();  // qnb is read cross-wave

    // out-GEMM: O[256 x 32] = matT * qn
    f32x4 accO[2][2];
#pragma unroll
    for (int mi = 0; mi < 2; ++mi)
#pragma unroll
      for (int nt = 0; nt < 2; ++nt) accO[mi][nt] = (f32x4){0.f, 0.f, 0.f, 0.f};
    const ushort_t* mrow0 = matT + ((size_t)b * kC + (2 * w) * 16 + l16) * kM + quad * 8;
    const ushort_t* mrow1 = mrow0 + 16 * kM;
#pragma unroll
    for (int ks = 0; ks < 4; ++ks) {
      short8 b0 = *(const short8*)&qnb[l16][ks * 32 + quad * 8];
      short8 b1 = *(const short8*)&qnb[16 + l16][ks * 32 + quad * 8];
      short8 a0 = *(const short8*)(mrow0 + ks * 32);
      short8 a1 = *(const short8*)(mrow1 + ks * 32);
      accO[0][0] = MFMA16(a0, b0, accO[0][0]);
      accO[0][1] = MFMA16(a0, b1, accO[0][1]);
      accO[1][0] = MFMA16(a1, b0, accO[1][0]);
      accO[1][1] = MFMA16(a1, b1, accO[1][1]);
    }
#pragma unroll
    for (int mi = 0; mi < 2; ++mi) {
#pragma unroll
      for (int r = 0; r < 4; ++r) {
        const int c = (2 * w + mi) * 16 + 4 * quad + r;
        size_t base = ((size_t)(b * kC + c)) * kN + n0;
        out[base + l16] = gm * tl0 * (vs_r[mi][r] + accO[mi][0][r]);
        out[base + 16 + l16] = gm * tl1 * (vs_r[mi][r] + accO[mi][1][r]);
      }
    }
  };

  for (int ti = 0; ti < 8; ti += 2) {
    step(ti, bufA, bufB);
    step(ti + 1, bufB, bufA);
  }
}

extern "C" void kernel_launch(void* const* d_in, const int* in_sizes, int n_in,
                              void* d_out, int out_size, void* d_ws, size_t ws_size,
                              hipStream_t stream) {
  (void)in_sizes; (void)n_in; (void)out_size; (void)ws_size;
  const float* x     = (const float*)d_in[0];
  const float* Wq    = (const float*)d_in[1];
  const float* bq    = (const float*)d_in[2];
  const float* Wk    = (const float*)d_in[3];
  const float* bk    = (const float*)d_in[4];
  const float* Wv    = (const float*)d_in[5];
  const float* bv    = (const float*)d_in[6];
  const float* gamma = (const float*)d_in[7];
  float* out = (float*)d_out;

  char* wsb = (char*)d_ws;
  float*    S    = (float*)(wsb + kOffS);
  float*    matF = (float*)(wsb + kOffMatF);
  float*    Ksum = (float*)(wsb + kOffKsum);
  float*    xsum = (float*)(wsb + kOffXsum);
  float*    vsum = (float*)(wsb + kOffVsum);
  ushort_t* Wkb  = (ushort_t*)(wsb + kOffWkb);
  ushort_t* Wqb  = (ushort_t*)(wsb + kOffWqb);
  ushort_t* matT = (ushort_t*)(wsb + kOffMatT);
  ushort_t* KnG  = (ushort_t*)(wsb + kOffKn);
  ushort_t* xb16 = (ushort_t*)(wsb + kOffXb16);

  k0_init<<<1024, 256, 0, stream>>>(Wq, Wk, (float*)wsb, Wkb, Wqb);
  k1a_proj<<<dim3(64, 8), 512, 0, stream>>>(x, bk, Wkb, KnG, xb16, Ksum, xsum);
  k1b_S<<<dim3(64, 8), 512, 0, stream>>>(KnG, xb16, S);
  k2_matrix<<<1032, 256, 0, stream>>>(S, Wv, xsum, bv, matF, vsum);
  k2b_cast<<<1024, 256, 0, stream>>>(matF, Ksum, bv, matT);
  k3_out<<<dim3(64, 8), 512, 0, stream>>>(xb16, bq, Wqb, matT, Ksum, vsum, gamma, out);
}

// Round 7
// 327.063 us; speedup vs baseline: 1.5553x; 1.3804x over previous
//
#include <hip/hip_runtime.h>
#include <math.h>

typedef unsigned short ushort_t;
typedef __attribute__((ext_vector_type(4))) float f32x4;
typedef __attribute__((ext_vector_type(8))) short short8;

#define MFMA16(a, b, c) __builtin_amdgcn_mfma_f32_16x16x32_bf16((a), (b), (c), 0, 0, 0)

// Problem dims (fixed)
constexpr int kB = 8;
constexpr int kC = 256;
constexpr int kM = 128;
constexpr int kN = 16384;

// ws layout (bytes, 256-aligned). Total ~69.9 MB.
constexpr size_t kOffSp   = 0;          // fp32 [8][64][128][256] private S partials
constexpr size_t kOffS    = 67108864;   // fp32 [8][128][256]
constexpr size_t kOffMatF = 68157440;   // fp32 [8][256][128]
constexpr size_t kOffKsum = 69206016;   // fp32 [8][128]
constexpr size_t kOffXsum = 69210112;   // fp32 [8][256]
constexpr size_t kOffVsum = 69218304;   // fp32 [8][256]
constexpr size_t kOffWkb  = 69226496;   // bf16 [128][256]
constexpr size_t kOffWqb  = 69292032;   // bf16 [128][256]
constexpr size_t kOffMatT = 69357568;   // bf16 [8][256][128]

__device__ __forceinline__ ushort_t f2bf(float f) {
  union { float f; unsigned u; } v; v.f = f;
  unsigned r = v.u + 0x7fffu + ((v.u >> 16) & 1u);
  return (ushort_t)(r >> 16);
}
__device__ __forceinline__ float bf2f(ushort_t h) {
  union { float f; unsigned u; } v; v.u = ((unsigned)h) << 16;
  return v.f;
}

// Barrier that drains LDS only (lgkmcnt(0)); global loads stay in flight.
__device__ __forceinline__ void sync_lds() {
  __atomic_signal_fence(__ATOMIC_SEQ_CST);
  __builtin_amdgcn_s_waitcnt(0xc07f);  // lgkmcnt(0), vmcnt/expcnt untouched
  __builtin_amdgcn_s_barrier();
  __atomic_signal_fence(__ATOMIC_SEQ_CST);
}

// ---------------- K0: zero matF/Ksum/xsum + cast weights to bf16 -------------
// S is fully overwritten by k1r and Sp by k1 -> neither needs zeroing.
__global__ void k0_init(const float* __restrict__ Wq, const float* __restrict__ Wk,
                        float* __restrict__ ws_f, ushort_t* __restrict__ Wkb,
                        ushort_t* __restrict__ Wqb) {
  int i = blockIdx.x * 256 + threadIdx.x;  // 1024 x 256 = 262144 threads
  // zero matF (262144 f) + Ksum (1024 f) + xsum (2048 f), contiguous at kOffMatF
  const int base = (int)(kOffMatF / 4);
  for (int j = i; j < 265216; j += 262144) ws_f[base + j] = 0.0f;
  if (i < kM * kC) {
    Wkb[i] = f2bf(Wk[i]);
    Wqb[i] = f2bf(Wq[i]);
  }
}

// ---------------- K1: K-proj (MFMA) -> L2-norm -> Sp[slice] = Kn * x^T -------
// grid (64, 8), block 512. r3-proven body (112 VGPR, no spill, 2 blocks/CU).
// ONLY change vs r3: the S flush is now PLAIN STORES to a per-block private
// slot instead of 16.7M device atomicAdds. Theory (k1b evidence, r6): global
// atomic throughput caps at ~150 G/s chip-wide -> the old flush alone was
// ~100 us and everything else hid under it. Plain 65 MB stores ~ 10 us.
__global__ __launch_bounds__(512, 2)
void k1_acc(const float* __restrict__ x, const float* __restrict__ bk,
            const ushort_t* __restrict__ Wkb, float* __restrict__ Sp,
            float* __restrict__ Ksum, float* __restrict__ xsum) {
  // Bank layouts verified r0-r5: xb_n pitch 40 (reads 8/bank uniform, writes
  // 4/bank min); xb_t pitch 256 + XOR key ((row>>1)&7)<<3 (reads 8/bank,
  // writes 2/bank free); knb pitch 40.
  __shared__ __align__(16) ushort_t xb_n[256][40];   // [ch][px]  (px-fastest)
  __shared__ __align__(16) ushort_t xb_t[32][256];   // [px][ch ^ key<<3]
  __shared__ __align__(16) ushort_t knb[128][40];    // [Krow][px]
  __shared__ __align__(16) float red[32][12];        // [px][wave]

  const int t = threadIdx.x;
  const int b = blockIdx.y;
  const int lane = t & 63, w = t >> 6, quad = lane >> 4, l16 = lane & 15;
  const int r8 = t >> 3;        // channel row-in-64 (0..63)
  const int px0 = 4 * (t & 7);  // owned pixel group
  const int key01 = ((px0 >> 1) & 7) << 3;
  const int key23 = key01 ^ 8;
  const int rk = ((l16 >> 1) & 7) << 3;

  float bk_r[4];
#pragma unroll
  for (int r = 0; r < 4; ++r) bk_r[r] = bk[16 * w + 4 * quad + r];

  f32x4 accS[16];
#pragma unroll
  for (int ct = 0; ct < 16; ++ct) accS[ct] = (f32x4){0.f, 0.f, 0.f, 0.f};
  float ksump[4] = {0.f, 0.f, 0.f, 0.f};
  float xs_p[4] = {0.f, 0.f, 0.f, 0.f};

  const float* xg = x + ((size_t)(b * kC) + r8) * kN + blockIdx.x * 256 + px0;

  float4 bufA[4], bufB[4];
#pragma unroll
  for (int p = 0; p < 4; ++p)
    bufA[p] = *(const float4*)(xg + (size_t)p * 64 * kN);

  auto step = [&](int ti, float4 (&cur)[4], float4 (&nxt)[4]) {
    sync_lds();  // previous tile's LDS consumers done
    if (ti < 7) {
#pragma unroll
      for (int p = 0; p < 4; ++p)
        nxt[p] = *(const float4*)(xg + (size_t)p * 64 * kN + (ti + 1) * 32);
    }
#pragma unroll
    for (int p = 0; p < 4; ++p) {
      float4 v = cur[p];
      const int rp = 64 * p + r8;
      xs_p[p] += v.x + v.y + v.z + v.w;
      ushort_t u0 = f2bf(v.x), u1 = f2bf(v.y), u2 = f2bf(v.z), u3 = f2bf(v.w);
      uint2 pk;
      pk.x = (unsigned)u0 | ((unsigned)u1 << 16);
      pk.y = (unsigned)u2 | ((unsigned)u3 << 16);
      *(uint2*)&xb_n[rp][px0] = pk;
      xb_t[px0 + 0][rp ^ key01] = u0;
      xb_t[px0 + 1][rp ^ key01] = u1;
      xb_t[px0 + 2][rp ^ key23] = u2;
      xb_t[px0 + 3][rp ^ key23] = u3;
    }
    sync_lds();  // stage done

    // ---- GEMM1: K[128x32] = Wk * x (wave w owns K rows 16w..16w+15) ----
    f32x4 acc1[2] = {{0.f, 0.f, 0.f, 0.f}, {0.f, 0.f, 0.f, 0.f}};
    const ushort_t* wkbase = Wkb + (16 * w + l16) * 256 + quad * 8;
#pragma unroll
    for (int ks = 0; ks < 8; ++ks) {
      short8 a = *(const short8*)(wkbase + ks * 32);
      short8 b0 = *(const short8*)&xb_t[l16][(ks * 32 + quad * 8) ^ rk];
      short8 b1 = *(const short8*)&xb_t[16 + l16][(ks * 32 + quad * 8) ^ rk];
      acc1[0] = MFMA16(a, b0, acc1[0]);
      acc1[1] = MFMA16(a, b1, acc1[1]);
    }
    float k0v[4], k1v[4];
    float ssq0 = 0.f, ssq1 = 0.f;
#pragma unroll
    for (int r = 0; r < 4; ++r) {
      k0v[r] = acc1[0][r] + bk_r[r];
      k1v[r] = acc1[1][r] + bk_r[r];
      ssq0 += k0v[r] * k0v[r];
      ssq1 += k1v[r] * k1v[r];
    }
    ssq0 += __shfl_xor(ssq0, 16); ssq0 += __shfl_xor(ssq0, 32);
    ssq1 += __shfl_xor(ssq1, 16); ssq1 += __shfl_xor(ssq1, 32);
    if (quad == 0) { red[l16][w] = ssq0; red[16 + l16][w] = ssq1; }
    sync_lds();  // red ready

    f32x4 ra = *(const f32x4*)&red[l16][0];
    f32x4 rb = *(const f32x4*)&red[l16][4];
    f32x4 rc = *(const f32x4*)&red[16 + l16][0];
    f32x4 rd = *(const f32x4*)&red[16 + l16][4];
    const float iv0 = rsqrtf(ra[0] + ra[1] + ra[2] + ra[3] + rb[0] + rb[1] + rb[2] + rb[3]);
    const float iv1 = rsqrtf(rc[0] + rc[1] + rc[2] + rc[3] + rd[0] + rd[1] + rd[2] + rd[3]);
#pragma unroll
    for (int r = 0; r < 4; ++r) {
      float kn0 = k0v[r] * iv0, kn1 = k1v[r] * iv1;
      ksump[r] += kn0 + kn1;
      knb[16 * w + 4 * quad + r][l16] = f2bf(kn0);
      knb[16 * w + 4 * quad + r][16 + l16] = f2bf(kn1);
    }
    // knb rows 16w..16w+15 are wave-private: DS pipe is in-order per wave.
    __builtin_amdgcn_s_waitcnt(0xc07f);

    // ---- GEMM2: S[128x256] += Kn * x^T (Kdim = 32 px) ----
    short8 a2 = *(const short8*)&knb[16 * w + l16][quad * 8];
#pragma unroll
    for (int ct = 0; ct < 16; ++ct) {
      short8 b2 = *(const short8*)&xb_n[ct * 16 + l16][quad * 8];
      accS[ct] = MFMA16(a2, b2, accS[ct]);
    }
  };

  for (int ti = 0; ti < 8; ti += 2) {
    step(ti, bufA, bufB);
    step(ti + 1, bufB, bufA);
  }

  // ---- flush: plain stores into this block's PRIVATE partial slot ----
  float* Sb = Sp + (((size_t)b * 64 + blockIdx.x) << 15);  // 32768 f / slot
#pragma unroll
  for (int ct = 0; ct < 16; ++ct)
#pragma unroll
    for (int r = 0; r < 4; ++r)
      Sb[(16 * w + 4 * quad + r) * 256 + ct * 16 + l16] = accS[ct][r];
  // Ksum/xsum atomics stay: ~150K ops total, negligible vs the 16.7M removed.
#pragma unroll
  for (int r = 0; r < 4; ++r) {
    float v = ksump[r];
    v += __shfl_xor(v, 1); v += __shfl_xor(v, 2);
    v += __shfl_xor(v, 4); v += __shfl_xor(v, 8);
    if (l16 == 0) atomicAdd(&Ksum[b * kM + 16 * w + 4 * quad + r], v);
  }
#pragma unroll
  for (int p = 0; p < 4; ++p) {
    float v = xs_p[p];
    v += __shfl_xor(v, 1); v += __shfl_xor(v, 2); v += __shfl_xor(v, 4);
    if ((t & 7) == 0) atomicAdd(&xsum[b * kC + 64 * p + r8], v);
  }
}

// ---------------- K1R: S = sum of 64 partial slots ---------------------------
// grid 1024 x 256, coalesced (r3-verified pattern, widened 16 -> 64 slices).
__global__ __launch_bounds__(256)
void k1_reduce(const float* __restrict__ Sp, float* __restrict__ S) {
  const int idx = blockIdx.x * 256 + threadIdx.x;  // 0..262143
  const int b = idx >> 15, rem = idx & 32767;
  const float* base = Sp + (((size_t)b * 64) << 15) + rem;
  float s0 = 0.f, s1 = 0.f, s2 = 0.f, s3 = 0.f;
#pragma unroll
  for (int p = 0; p < 16; ++p) {
    s0 += base[(size_t)(4 * p + 0) << 15];
    s1 += base[(size_t)(4 * p + 1) << 15];
    s2 += base[(size_t)(4 * p + 2) << 15];
    s3 += base[(size_t)(4 * p + 3) << 15];
  }
  S[idx] = (s0 + s1) + (s2 + s3);
}

// ---------------- K2: matF += partial(S*Wv^T) via hi/lo bf16 MFMA ------------
// c-contraction split x4 -> 1024 blocks for occupancy; 1M fp32 atomics ~ 7 us
// at the atomic-throughput cap (acceptable). Blocks 1024..1031 compute
// vsum = Wv*xsum + N*bv. (r4/r5/r6-verified.)
__global__ __launch_bounds__(256, 4)
void k2_matrix(const float* __restrict__ S, const float* __restrict__ Wv,
               const float* __restrict__ xsum, const float* __restrict__ bv,
               float* __restrict__ matF, float* __restrict__ vsum) {
  const int bx = blockIdx.x;
  const int t = threadIdx.x;
  if (bx >= 1024) {  // vsum blocks (one per batch)
    const int b = bx - 1024;
    const float4* wr = (const float4*)(Wv + (size_t)t * 256);
    const float4* xs = (const float4*)(xsum + b * 256);
    float v = 0.f;
#pragma unroll 8
    for (int i = 0; i < 64; ++i) {
      float4 a = wr[i], xx = xs[i];
      v += a.x * xx.x + a.y * xx.y + a.z * xx.z + a.w * xx.w;
    }
    vsum[b * 256 + t] = v + 16384.f * bv[t];
    return;
  }
  const int lane = t & 63, w = t >> 6, quad = lane >> 4, l16 = lane & 15;
  const int b = bx >> 7, rr_ = bx & 127;
  const int ct = rr_ >> 3, mt = (rr_ >> 2) & 1, kq = rr_ & 3;
  const int c0 = ct * 16;
  const int m0 = mt * 64 + w * 16;

  const float* arow = Wv + (size_t)(c0 + l16) * 256 + kq * 64 + quad * 8;
  const float* brow = S + ((size_t)b * kM + m0 + l16) * 256 + kq * 64 + quad * 8;

  f32x4 acc = (f32x4){0.f, 0.f, 0.f, 0.f};
#pragma unroll
  for (int ks = 0; ks < 2; ++ks) {
    float4 a0 = *(const float4*)(arow + ks * 32);
    float4 a1 = *(const float4*)(arow + ks * 32 + 4);
    float4 b0 = *(const float4*)(brow + ks * 32);
    float4 b1 = *(const float4*)(brow + ks * 32 + 4);
    float av[8] = {a0.x, a0.y, a0.z, a0.w, a1.x, a1.y, a1.z, a1.w};
    float bw[8] = {b0.x, b0.y, b0.z, b0.w, b1.x, b1.y, b1.z, b1.w};
    short8 ah, al, bh, bl;
#pragma unroll
    for (int i = 0; i < 8; ++i) {
      ushort_t h = f2bf(av[i]);
      ah[i] = (short)h;
      al[i] = (short)f2bf(av[i] - bf2f(h));
      ushort_t g = f2bf(bw[i]);
      bh[i] = (short)g;
      bl[i] = (short)f2bf(bw[i] - bf2f(g));
    }
    acc = MFMA16(ah, bh, acc);
    acc = MFMA16(ah, bl, acc);
    acc = MFMA16(al, bh, acc);
  }
#pragma unroll
  for (int r = 0; r < 4; ++r)
    atomicAdd(&matF[((size_t)b * kC + c0 + 4 * quad + r) * kM + m0 + l16], acc[r]);
}

// ---------------- K2b: matT = bf16(matF + Ksum*bv^T) -------------------------
__global__ __launch_bounds__(256)
void k2b_cast(const float* __restrict__ matF, const float* __restrict__ Ksum,
              const float* __restrict__ bv, ushort_t* __restrict__ matT) {
  const int idx = blockIdx.x * 256 + threadIdx.x;  // 262144 = 8*256*128
  const int m = idx & 127, c = (idx >> 7) & 255, b = idx >> 15;
  matT[idx] = f2bf(matF[idx] + Ksum[b * 128 + m] * bv[c]);
}

// ---------------- K3: Q-proj -> norm/tailor -> out = g*t*(vsum + matT*qn) ----
// grid (64, 8), block 512. Byte-identical to the r3 343-us config.
__global__ __launch_bounds__(512, 2)
void k3_out(const float* __restrict__ x, const float* __restrict__ bq,
            const ushort_t* __restrict__ Wqb, const ushort_t* __restrict__ matT,
            const float* __restrict__ Ksum, const float* __restrict__ vsum,
            const float* __restrict__ gamma, float* __restrict__ out) {
  __shared__ __align__(16) ushort_t xb_t[32][256];   // [px][ch ^ key<<3]
  __shared__ __align__(16) ushort_t qnb[32][136];    // [px][m]
  __shared__ __align__(16) float red[32][12];
  __shared__ __align__(16) float red2[32][12];

  const int t = threadIdx.x;
  const int b = blockIdx.y;
  const int lane = t & 63, w = t >> 6, quad = lane >> 4, l16 = lane & 15;
  const int r8 = t >> 3;
  const int px0 = 4 * (t & 7);
  const int key01 = ((px0 >> 1) & 7) << 3;
  const int key23 = key01 ^ 8;
  const int rk = ((l16 >> 1) & 7) << 3;
  const float gm = gamma[0];

  float bq_r[4], ks_r[4], vs_r[2][4];
#pragma unroll
  for (int r = 0; r < 4; ++r) {
    bq_r[r] = bq[16 * w + 4 * quad + r];
    ks_r[r] = Ksum[b * kM + 16 * w + 4 * quad + r] + 1e-6f;
  }
#pragma unroll
  for (int mi = 0; mi < 2; ++mi)
#pragma unroll
    for (int r = 0; r < 4; ++r)
      vs_r[mi][r] = vsum[b * kC + (2 * w + mi) * 16 + 4 * quad + r];

  const float* xg = x + ((size_t)(b * kC) + r8) * kN + blockIdx.x * 256 + px0;

  float4 bufA[4], bufB[4];
#pragma unroll
  for (int p = 0; p < 4; ++p)
    bufA[p] = *(const float4*)(xg + (size_t)p * 64 * kN);

  auto step = [&](int ti, float4 (&cur)[4], float4 (&nxt)[4]) {
    const int n0 = blockIdx.x * 256 + ti * 32;
    sync_lds();
    if (ti < 7) {
#pragma unroll
      for (int p = 0; p < 4; ++p)
        nxt[p] = *(const float4*)(xg + (size_t)p * 64 * kN + (ti + 1) * 32);
    }
#pragma unroll
    for (int p = 0; p < 4; ++p) {
      float4 v = cur[p];
      const int rp = 64 * p + r8;
      xb_t[px0 + 0][rp ^ key01] = f2bf(v.x);
      xb_t[px0 + 1][rp ^ key01] = f2bf(v.y);
      xb_t[px0 + 2][rp ^ key23] = f2bf(v.z);
      xb_t[px0 + 3][rp ^ key23] = f2bf(v.w);
    }
    sync_lds();

    // Q projection
    f32x4 acc1[2] = {{0.f, 0.f, 0.f, 0.f}, {0.f, 0.f, 0.f, 0.f}};
    const ushort_t* wqbase = Wqb + (16 * w + l16) * 256 + quad * 8;
#pragma unroll
    for (int ks = 0; ks < 8; ++ks) {
      short8 a = *(const short8*)(wqbase + ks * 32);
      short8 b0 = *(const short8*)&xb_t[l16][(ks * 32 + quad * 8) ^ rk];
      short8 b1 = *(const short8*)&xb_t[16 + l16][(ks * 32 + quad * 8) ^ rk];
      acc1[0] = MFMA16(a, b0, acc1[0]);
      acc1[1] = MFMA16(a, b1, acc1[1]);
    }
    float q0v[4], q1v[4];
    float ssq0 = 0.f, ssq1 = 0.f, dot0 = 0.f, dot1 = 0.f;
#pragma unroll
    for (int r = 0; r < 4; ++r) {
      q0v[r] = acc1[0][r] + bq_r[r];
      q1v[r] = acc1[1][r] + bq_r[r];
      ssq0 += q0v[r] * q0v[r]; ssq1 += q1v[r] * q1v[r];
      dot0 += q0v[r] * ks_r[r]; dot1 += q1v[r] * ks_r[r];
    }
    ssq0 += __shfl_xor(ssq0, 16); ssq0 += __shfl_xor(ssq0, 32);
    ssq1 += __shfl_xor(ssq1, 16); ssq1 += __shfl_xor(ssq1, 32);
    dot0 += __shfl_xor(dot0, 16); dot0 += __shfl_xor(dot0, 32);
    dot1 += __shfl_xor(dot1, 16); dot1 += __shfl_xor(dot1, 32);
    if (quad == 0) {
      red[l16][w] = ssq0;  red[16 + l16][w] = ssq1;
      red2[l16][w] = dot0; red2[16 + l16][w] = dot1;
    }
    sync_lds();
    f32x4 ra = *(const f32x4*)&red[l16][0];
    f32x4 rb = *(const f32x4*)&red[l16][4];
    f32x4 rc = *(const f32x4*)&red[16 + l16][0];
    f32x4 rd = *(const f32x4*)&red[16 + l16][4];
    f32x4 da = *(const f32x4*)&red2[l16][0];
    f32x4 db = *(const f32x4*)&red2[l16][4];
    f32x4 dc = *(const f32x4*)&red2[16 + l16][0];
    f32x4 dd = *(const f32x4*)&red2[16 + l16][4];
    const float iv0 = rsqrtf(ra[0] + ra[1] + ra[2] + ra[3] + rb[0] + rb[1] + rb[2] + rb[3]);
    const float iv1 = rsqrtf(rc[0] + rc[1] + rc[2] + rc[3] + rd[0] + rd[1] + rd[2] + rd[3]);
    const float d0 = da[0] + da[1] + da[2] + da[3] + db[0] + db[1] + db[2] + db[3];
    const float d1 = dc[0] + dc[1] + dc[2] + dc[3] + dd[0] + dd[1] + dd[2] + dd[3];
    const float tl0 = 1.f / (16384.f + d0 * iv0);
    const float tl1 = 1.f / (16384.f + d1 * iv1);
    {
      ushort_t q0b[4], q1b[4];
#pragma unroll
      for (int r = 0; r < 4; ++r) {
        q0b[r] = f2bf(q0v[r] * iv0);
        q1b[r] = f2bf(q1v[r] * iv1);
      }
      uint2 p0, p1;
      p0.x = (unsigned)q0b[0] | ((unsigned)q0b[1] << 16);
      p0.y = (unsigned)q0b[2] | ((unsigned)q0b[3] << 16);
      p1.x = (unsigned)q1b[0] | ((unsigned)q1b[1] << 16);
      p1.y = (unsigned)q1b[2] | ((unsigned)q1b[3] << 16);
      *(uint2*)&qnb[l16][16 * w + 4 * quad] = p0;
      *(uint2*)&qnb[16 + l16][16 * w + 4 * quad] = p1;
    }
    sync_lds();  // qnb is read cross-wave

    // out-GEMM: O[256 x 32] = matT * qn  (wave w owns c-tiles 2w, 2w+1)
    f32x4 accO[2][2];
#pragma unroll
    for (int mi = 0; mi < 2; ++mi)
#pragma unroll
      for (int nt = 0; nt < 2; ++nt) accO[mi][nt] = (f32x4){0.f, 0.f, 0.f, 0.f};
    const ushort_t* mrow0 = matT + ((size_t)b * kC + (2 * w) * 16 + l16) * kM + quad * 8;
    const ushort_t* mrow1 = mrow0 + 16 * kM;
#pragma unroll
    for (int ks = 0; ks < 4; ++ks) {
      short8 b0 = *(const short8*)&qnb[l16][ks * 32 + quad * 8];
      short8 b1 = *(const short8*)&qnb[16 + l16][ks * 32 + quad * 8];
      short8 a0 = *(const short8*)(mrow0 + ks * 32);
      short8 a1 = *(const short8*)(mrow1 + ks * 32);
      accO[0][0] = MFMA16(a0, b0, accO[0][0]);
      accO[0][1] = MFMA16(a0, b1, accO[0][1]);
      accO[1][0] = MFMA16(a1, b0, accO[1][0]);
      accO[1][1] = MFMA16(a1, b1, accO[1][1]);
    }
#pragma unroll
    for (int mi = 0; mi < 2; ++mi) {
#pragma unroll
      for (int r = 0; r < 4; ++r) {
        const int c = (2 * w + mi) * 16 + 4 * quad + r;
        size_t base = ((size_t)(b * kC + c)) * kN + n0;
        out[base + l16] = gm * tl0 * (vs_r[mi][r] + accO[mi][0][r]);
        out[base + 16 + l16] = gm * tl1 * (vs_r[mi][r] + accO[mi][1][r]);
      }
    }
  };

  for (int ti = 0; ti < 8; ti += 2) {
    step(ti, bufA, bufB);
    step(ti + 1, bufB, bufA);
  }
}

extern "C" void kernel_launch(void* const* d_in, const int* in_sizes, int n_in,
                              void* d_out, int out_size, void* d_ws, size_t ws_size,
                              hipStream_t stream) {
  (void)in_sizes; (void)n_in; (void)out_size; (void)ws_size;
  const float* x     = (const float*)d_in[0];
  const float* Wq    = (const float*)d_in[1];
  const float* bq    = (const float*)d_in[2];
  const float* Wk    = (const float*)d_in[3];
  const float* bk    = (const float*)d_in[4];
  const float* Wv    = (const float*)d_in[5];
  const float* bv    = (const float*)d_in[6];
  const float* gamma = (const float*)d_in[7];
  float* out = (float*)d_out;

  char* wsb = (char*)d_ws;
  float*    Sp   = (float*)(wsb + kOffSp);
  float*    S    = (float*)(wsb + kOffS);
  float*    matF = (float*)(wsb + kOffMatF);
  float*    Ksum = (float*)(wsb + kOffKsum);
  float*    xsum = (float*)(wsb + kOffXsum);
  float*    vsum = (float*)(wsb + kOffVsum);
  ushort_t* Wkb  = (ushort_t*)(wsb + kOffWkb);
  ushort_t* Wqb  = (ushort_t*)(wsb + kOffWqb);
  ushort_t* matT = (ushort_t*)(wsb + kOffMatT);

  k0_init<<<1024, 256, 0, stream>>>(Wq, Wk, (float*)wsb, Wkb, Wqb);
  k1_acc<<<dim3(64, 8), 512, 0, stream>>>(x, bk, Wkb, Sp, Ksum, xsum);
  k1_reduce<<<1024, 256, 0, stream>>>(Sp, S);
  k2_matrix<<<1032, 256, 0, stream>>>(S, Wv, xsum, bv, matF, vsum);
  k2b_cast<<<1024, 256, 0, stream>>>(matF, Ksum, bv, matT);
  k3_out<<<dim3(64, 8), 512, 0, stream>>>(x, bq, Wqb, matT, Ksum, vsum, gamma, out);
}